// Round 1
// baseline (12271.655 us; speedup 1.0000x reference)
//
#include <hip/hip_runtime.h>

#define N_USERS 100000
#define N_ITEMS 50000
#define N_NODES 150000   // N_USERS + N_ITEMS
#define N_EDGES 4800000
#define EMB 64
#define N_LAYERS 3

// ---------------------------------------------------------------------------
// k_init: out = ego = concat(user, item); cur = ego.  float4-vectorized.
// total float4 elems: 150000*64/4 = 2,400,000 ; user part = 1,600,000
// ---------------------------------------------------------------------------
__global__ void k_init(const float4* __restrict__ user,
                       const float4* __restrict__ item,
                       float4* __restrict__ out,
                       float4* __restrict__ cur) {
    int i = blockIdx.x * blockDim.x + threadIdx.x;
    const int total4 = N_NODES * EMB / 4;       // 2,400,000
    const int user4  = N_USERS * EMB / 4;       // 1,600,000
    if (i >= total4) return;
    float4 v = (i < user4) ? user[i] : item[i - user4];
    out[i] = v;
    cur[i] = v;
}

// ---------------------------------------------------------------------------
// k_spmm: y[dst] += w * x[src]   (atomic scatter)
// 16 threads per edge; each thread handles one float4 (4 dims) of the 64-dim
// embedding. Gather of x[src] is a coalesced 64B-per-16-lane segment.
// ---------------------------------------------------------------------------
__global__ void k_spmm(const int*   __restrict__ src,
                       const int*   __restrict__ dst,
                       const float* __restrict__ w,
                       const float* __restrict__ x,
                       float*       __restrict__ y) {
    long long t = (long long)blockIdx.x * blockDim.x + threadIdx.x;
    int e = (int)(t >> 4);
    if (e >= N_EDGES) return;
    int q = (int)(t & 15);

    int   s  = src[e];
    int   d  = dst[e];
    float we = w[e];

    const float4* xs = (const float4*)(x + (long long)s * EMB);
    float4 v = xs[q];

    float* yd = y + (long long)d * EMB + q * 4;
    atomicAdd(yd + 0, we * v.x);
    atomicAdd(yd + 1, we * v.y);
    atomicAdd(yd + 2, we * v.z);
    atomicAdd(yd + 3, we * v.w);
}

// ---------------------------------------------------------------------------
// k_acc: out = (out + buf) * scale   (scale=1 mid-layers, 0.25 on the last)
// ---------------------------------------------------------------------------
__global__ void k_acc(float4* __restrict__ out,
                      const float4* __restrict__ buf,
                      float scale) {
    int i = blockIdx.x * blockDim.x + threadIdx.x;
    const int total4 = N_NODES * EMB / 4;
    if (i >= total4) return;
    float4 o = out[i];
    float4 b = buf[i];
    o.x = (o.x + b.x) * scale;
    o.y = (o.y + b.y) * scale;
    o.z = (o.z + b.z) * scale;
    o.w = (o.w + b.w) * scale;
    out[i] = o;
}

extern "C" void kernel_launch(void* const* d_in, const int* in_sizes, int n_in,
                              void* d_out, int out_size, void* d_ws, size_t ws_size,
                              hipStream_t stream) {
    const float* user_emb = (const float*)d_in[0];
    const float* item_emb = (const float*)d_in[1];
    const float* edge_w   = (const float*)d_in[2];
    const int*   edge_src = (const int*)d_in[3];
    const int*   edge_dst = (const int*)d_in[4];
    float* out = (float*)d_out;

    const size_t feat_elems = (size_t)N_NODES * EMB;        // 9.6M floats
    const size_t feat_bytes = feat_elems * sizeof(float);   // 38.4 MB

    float* buf0 = (float*)d_ws;
    float* buf1 = buf0 + feat_elems;

    const int block = 256;

    // init: out = ego, buf0 = ego
    {
        int total4 = (int)(feat_elems / 4);
        int grid = (total4 + block - 1) / block;
        k_init<<<grid, block, 0, stream>>>((const float4*)user_emb,
                                           (const float4*)item_emb,
                                           (float4*)out, (float4*)buf0);
    }

    float* cur = buf0;
    float* nxt = buf1;
    for (int layer = 0; layer < N_LAYERS; ++layer) {
        hipMemsetAsync(nxt, 0, feat_bytes, stream);

        long long threads = (long long)N_EDGES * 16;
        int grid = (int)((threads + block - 1) / block);
        k_spmm<<<grid, block, 0, stream>>>(edge_src, edge_dst, edge_w, cur, nxt);

        float scale = (layer == N_LAYERS - 1) ? (1.0f / (N_LAYERS + 1)) : 1.0f;
        int total4 = (int)(feat_elems / 4);
        int agrid = (total4 + block - 1) / block;
        k_acc<<<agrid, block, 0, stream>>>((float4*)out, (const float4*)nxt, scale);

        float* tmp = cur; cur = nxt; nxt = tmp;
    }
}

// Round 2
// 1272.910 us; speedup vs baseline: 9.6406x; 9.6406x over previous
//
#include <hip/hip_runtime.h>

#define N_USERS 100000
#define N_ITEMS 50000
#define N_NODES 150000   // N_USERS + N_ITEMS
#define N_EDGES 4800000
#define EMB 64
#define N_LAYERS 3

#define SCAN_BLK 1024                       // elements per scan block
#define N_SCAN_BLKS ((N_NODES + SCAN_BLK - 1) / SCAN_BLK)   // 147

// ---------------------------------------------------------------------------
// k_init: out = ego = concat(user, item); cur = ego.  float4-vectorized.
// ---------------------------------------------------------------------------
__global__ void k_init(const float4* __restrict__ user,
                       const float4* __restrict__ item,
                       float4* __restrict__ out,
                       float4* __restrict__ cur) {
    int i = blockIdx.x * blockDim.x + threadIdx.x;
    const int total4 = N_NODES * EMB / 4;
    const int user4  = N_USERS * EMB / 4;
    if (i >= total4) return;
    float4 v = (i < user4) ? user[i] : item[i - user4];
    out[i] = v;
    cur[i] = v;
}

// ---------------------------------------------------------------------------
// CSR build: histogram over dst
// ---------------------------------------------------------------------------
__global__ void k_count(const int* __restrict__ dst, int* __restrict__ cnt) {
    int i = blockIdx.x * blockDim.x + threadIdx.x;
    if (i >= N_EDGES) return;
    atomicAdd(&cnt[dst[i]], 1);
}

// Per-block inclusive scan (Hillis-Steele in LDS) -> exclusive local values
// row_ptr[i] = exclusive-within-block; blk_sums[b] = block total
__global__ void k_scan_local(const int* __restrict__ cnt,
                             int* __restrict__ row_ptr,
                             int* __restrict__ blk_sums) {
    __shared__ int tmp[SCAN_BLK];
    int tid = threadIdx.x;
    int gi  = blockIdx.x * SCAN_BLK + tid;
    int val = (gi < N_NODES) ? cnt[gi] : 0;
    tmp[tid] = val;
    __syncthreads();
    for (int off = 1; off < SCAN_BLK; off <<= 1) {
        int t = 0;
        if (tid >= off) t = tmp[tid - off];
        __syncthreads();
        if (tid >= off) tmp[tid] += t;
        __syncthreads();
    }
    if (gi < N_NODES) row_ptr[gi] = tmp[tid] - val;   // exclusive
    if (tid == SCAN_BLK - 1) blk_sums[blockIdx.x] = tmp[tid];
}

// Scan the 147 block sums (single block) -> exclusive block offsets
__global__ void k_scan_blk(const int* __restrict__ blk_sums,
                           int* __restrict__ blk_offs) {
    __shared__ int tmp[256];
    int tid = threadIdx.x;
    int val = (tid < N_SCAN_BLKS) ? blk_sums[tid] : 0;
    tmp[tid] = val;
    __syncthreads();
    for (int off = 1; off < 256; off <<= 1) {
        int t = 0;
        if (tid >= off) t = tmp[tid - off];
        __syncthreads();
        if (tid >= off) tmp[tid] += t;
        __syncthreads();
    }
    if (tid < N_SCAN_BLKS) blk_offs[tid] = tmp[tid] - val;  // exclusive
}

// Add block offsets; produce final row_ptr and init cursor
__global__ void k_addoff(int* __restrict__ row_ptr,
                         const int* __restrict__ blk_offs,
                         int* __restrict__ cursor) {
    int i = blockIdx.x * blockDim.x + threadIdx.x;
    if (i < N_NODES) {
        int v = row_ptr[i] + blk_offs[i >> 10];
        row_ptr[i] = v;
        cursor[i]  = v;
    }
    if (i == 0) row_ptr[N_NODES] = N_EDGES;
}

// Scatter edges into dst-sorted pair array {src, w}
__global__ void k_scatter(const int*   __restrict__ src,
                          const int*   __restrict__ dst,
                          const float* __restrict__ w,
                          int* __restrict__ cursor,
                          int2* __restrict__ pairs) {
    int i = blockIdx.x * blockDim.x + threadIdx.x;
    if (i >= N_EDGES) return;
    int d = dst[i];
    int pos = atomicAdd(&cursor[d], 1);
    pairs[pos] = make_int2(src[i], __float_as_int(w[i]));
}

// ---------------------------------------------------------------------------
// k_gather: one wave (64 lanes = EMB dims) per destination node.
//   nxt[d] = sum_{edges into d} w * x[src]
//   out[d] = (out[d] + nxt[d]) * scale      (fused accumulate)
// No atomics: each output element written exactly once.
// ---------------------------------------------------------------------------
__global__ __launch_bounds__(256) void k_gather(const int*  __restrict__ row_ptr,
                                                const int2* __restrict__ pairs,
                                                const float* __restrict__ x,
                                                float* __restrict__ nxt,
                                                float* __restrict__ out,
                                                float scale) {
    int wave = (blockIdx.x * blockDim.x + threadIdx.x) >> 6;
    int lane = threadIdx.x & 63;
    if (wave >= N_NODES) return;
    int beg = row_ptr[wave];
    int end = row_ptr[wave + 1];
    float acc = 0.f;
    int j = beg;
    for (; j + 3 < end; j += 4) {
        int2 p0 = pairs[j];
        int2 p1 = pairs[j + 1];
        int2 p2 = pairs[j + 2];
        int2 p3 = pairs[j + 3];
        float a0 = x[(size_t)p0.x * EMB + lane];
        float a1 = x[(size_t)p1.x * EMB + lane];
        float a2 = x[(size_t)p2.x * EMB + lane];
        float a3 = x[(size_t)p3.x * EMB + lane];
        acc += __int_as_float(p0.y) * a0;
        acc += __int_as_float(p1.y) * a1;
        acc += __int_as_float(p2.y) * a2;
        acc += __int_as_float(p3.y) * a3;
    }
    for (; j < end; ++j) {
        int2 p = pairs[j];
        acc += __int_as_float(p.y) * x[(size_t)p.x * EMB + lane];
    }
    size_t o = (size_t)wave * EMB + lane;
    nxt[o] = acc;
    out[o] = (out[o] + acc) * scale;
}

// ---------------------------------------------------------------------------
// Fallback (round-1 proven path) if ws_size is too small for CSR
// ---------------------------------------------------------------------------
__global__ void k_spmm(const int*   __restrict__ src,
                       const int*   __restrict__ dst,
                       const float* __restrict__ w,
                       const float* __restrict__ x,
                       float*       __restrict__ y) {
    long long t = (long long)blockIdx.x * blockDim.x + threadIdx.x;
    int e = (int)(t >> 4);
    if (e >= N_EDGES) return;
    int q = (int)(t & 15);
    int   s  = src[e];
    int   d  = dst[e];
    float we = w[e];
    const float4* xs = (const float4*)(x + (long long)s * EMB);
    float4 v = xs[q];
    float* yd = y + (long long)d * EMB + q * 4;
    atomicAdd(yd + 0, we * v.x);
    atomicAdd(yd + 1, we * v.y);
    atomicAdd(yd + 2, we * v.z);
    atomicAdd(yd + 3, we * v.w);
}

__global__ void k_acc(float4* __restrict__ out,
                      const float4* __restrict__ buf,
                      float scale) {
    int i = blockIdx.x * blockDim.x + threadIdx.x;
    const int total4 = N_NODES * EMB / 4;
    if (i >= total4) return;
    float4 o = out[i];
    float4 b = buf[i];
    o.x = (o.x + b.x) * scale;
    o.y = (o.y + b.y) * scale;
    o.z = (o.z + b.z) * scale;
    o.w = (o.w + b.w) * scale;
    out[i] = o;
}

extern "C" void kernel_launch(void* const* d_in, const int* in_sizes, int n_in,
                              void* d_out, int out_size, void* d_ws, size_t ws_size,
                              hipStream_t stream) {
    const float* user_emb = (const float*)d_in[0];
    const float* item_emb = (const float*)d_in[1];
    const float* edge_w   = (const float*)d_in[2];
    const int*   edge_src = (const int*)d_in[3];
    const int*   edge_dst = (const int*)d_in[4];
    float* out = (float*)d_out;

    const size_t feat_elems = (size_t)N_NODES * EMB;        // 9.6M floats
    const size_t feat_bytes = feat_elems * sizeof(float);   // 38.4 MB

    // ---- workspace layout ----
    char* ws = (char*)d_ws;
    size_t off = 0;
    float* buf0 = (float*)(ws + off); off += feat_bytes;
    float* buf1 = (float*)(ws + off); off += feat_bytes;
    int* row_ptr = (int*)(ws + off);  off += ((size_t)(N_NODES + 1) * 4 + 63) / 64 * 64;
    int* cursor  = (int*)(ws + off);  off += ((size_t)N_NODES * 4 + 63) / 64 * 64;  // doubles as cnt
    int* blk_sums = (int*)(ws + off); off += 1024;
    int* blk_offs = (int*)(ws + off); off += 1024;
    int2* pairs  = (int2*)(ws + off); off += (size_t)N_EDGES * 8;
    const size_t needed = off;

    const int block = 256;
    const int total4 = (int)(feat_elems / 4);
    const int fgrid = (total4 + block - 1) / block;

    if (ws_size >= needed) {
        // ---------- CSR gather path ----------
        int* cnt = cursor;  // reused: cnt before scan, cursor after
        hipMemsetAsync(cnt, 0, (size_t)N_NODES * 4, stream);

        k_init<<<fgrid, block, 0, stream>>>((const float4*)user_emb,
                                            (const float4*)item_emb,
                                            (float4*)out, (float4*)buf0);

        int egrid = (N_EDGES + block - 1) / block;
        k_count<<<egrid, block, 0, stream>>>(edge_dst, cnt);
        k_scan_local<<<N_SCAN_BLKS, SCAN_BLK, 0, stream>>>(cnt, row_ptr, blk_sums);
        k_scan_blk<<<1, 256, 0, stream>>>(blk_sums, blk_offs);
        int agrid = (N_NODES + block - 1) / block;
        k_addoff<<<agrid, block, 0, stream>>>(row_ptr, blk_offs, cursor);
        k_scatter<<<egrid, block, 0, stream>>>(edge_src, edge_dst, edge_w, cursor, pairs);

        float* cur = buf0;
        float* nxt = buf1;
        for (int layer = 0; layer < N_LAYERS; ++layer) {
            float scale = (layer == N_LAYERS - 1) ? (1.0f / (N_LAYERS + 1)) : 1.0f;
            int ggrid = (N_NODES * (EMB / 4) * 4 + block - 1) / block; // 150000 waves / 4 per block
            ggrid = (N_NODES + 3) / 4;
            k_gather<<<ggrid, block, 0, stream>>>(row_ptr, pairs, cur, nxt, out, scale);
            float* tmp = cur; cur = nxt; nxt = tmp;
        }
    } else {
        // ---------- fallback: atomic scatter path ----------
        k_init<<<fgrid, block, 0, stream>>>((const float4*)user_emb,
                                            (const float4*)item_emb,
                                            (float4*)out, (float4*)buf0);
        float* cur = buf0;
        float* nxt = buf1;
        for (int layer = 0; layer < N_LAYERS; ++layer) {
            hipMemsetAsync(nxt, 0, feat_bytes, stream);
            long long threads = (long long)N_EDGES * 16;
            int grid = (int)((threads + block - 1) / block);
            k_spmm<<<grid, block, 0, stream>>>(edge_src, edge_dst, edge_w, cur, nxt);
            float scale = (layer == N_LAYERS - 1) ? (1.0f / (N_LAYERS + 1)) : 1.0f;
            k_acc<<<fgrid, block, 0, stream>>>((float4*)out, (const float4*)nxt, scale);
            float* tmp = cur; cur = nxt; nxt = tmp;
        }
    }
}

// Round 4
// 1034.510 us; speedup vs baseline: 11.8623x; 1.2304x over previous
//
#include <hip/hip_runtime.h>

#define N_USERS 100000
#define N_ITEMS 50000
#define N_NODES 150000   // N_USERS + N_ITEMS
#define N_EDGES 4800000
#define EMB 64
#define N_LAYERS 3

#define SCAN_BLK 1024
#define N_SCAN_BLKS ((N_NODES + SCAN_BLK - 1) / SCAN_BLK)   // 147

// native vector types for __builtin_nontemporal_* (HIP int2/int4 are classes)
typedef int  vi2 __attribute__((ext_vector_type(2)));
typedef int  vi4 __attribute__((ext_vector_type(4)));

// ---------------------------------------------------------------------------
// k_init: out = ego = concat(user, item); cur = ego.
// ---------------------------------------------------------------------------
__global__ void k_init(const float4* __restrict__ user,
                       const float4* __restrict__ item,
                       float4* __restrict__ out,
                       float4* __restrict__ cur) {
    int i = blockIdx.x * blockDim.x + threadIdx.x;
    const int total4 = N_NODES * EMB / 4;
    const int user4  = N_USERS * EMB / 4;
    if (i >= total4) return;
    float4 v = (i < user4) ? user[i] : item[i - user4];
    out[i] = v;
    cur[i] = v;
}

// ---------------------------------------------------------------------------
// k_count_rank: histogram over dst + per-edge rank (coalesced store).
// The atomic's return value is free — it becomes the edge's slot rank.
// ---------------------------------------------------------------------------
__global__ void k_count_rank(const int* __restrict__ dst,
                             int* __restrict__ cnt,
                             int* __restrict__ rank) {
    int i = blockIdx.x * blockDim.x + threadIdx.x;
    if (i >= N_EDGES) return;
    rank[i] = atomicAdd(&cnt[dst[i]], 1);
}

// plain count (fallback path, no rank array)
__global__ void k_count(const int* __restrict__ dst, int* __restrict__ cnt) {
    int i = blockIdx.x * blockDim.x + threadIdx.x;
    if (i >= N_EDGES) return;
    atomicAdd(&cnt[dst[i]], 1);
}

// Per-block scan (Hillis-Steele in LDS) -> exclusive local values
__global__ void k_scan_local(const int* __restrict__ cnt,
                             int* __restrict__ row_ptr,
                             int* __restrict__ blk_sums) {
    __shared__ int tmp[SCAN_BLK];
    int tid = threadIdx.x;
    int gi  = blockIdx.x * SCAN_BLK + tid;
    int val = (gi < N_NODES) ? cnt[gi] : 0;
    tmp[tid] = val;
    __syncthreads();
    for (int off = 1; off < SCAN_BLK; off <<= 1) {
        int t = 0;
        if (tid >= off) t = tmp[tid - off];
        __syncthreads();
        if (tid >= off) tmp[tid] += t;
        __syncthreads();
    }
    if (gi < N_NODES) row_ptr[gi] = tmp[tid] - val;   // exclusive
    if (tid == SCAN_BLK - 1) blk_sums[blockIdx.x] = tmp[tid];
}

__global__ void k_scan_blk(const int* __restrict__ blk_sums,
                           int* __restrict__ blk_offs) {
    __shared__ int tmp[256];
    int tid = threadIdx.x;
    int val = (tid < N_SCAN_BLKS) ? blk_sums[tid] : 0;
    tmp[tid] = val;
    __syncthreads();
    for (int off = 1; off < 256; off <<= 1) {
        int t = 0;
        if (tid >= off) t = tmp[tid - off];
        __syncthreads();
        if (tid >= off) tmp[tid] += t;
        __syncthreads();
    }
    if (tid < N_SCAN_BLKS) blk_offs[tid] = tmp[tid] - val;  // exclusive
}

__global__ void k_addoff(int* __restrict__ row_ptr,
                         const int* __restrict__ blk_offs,
                         int* __restrict__ cursor) {
    int i = blockIdx.x * blockDim.x + threadIdx.x;
    if (i < N_NODES) {
        int v = row_ptr[i] + blk_offs[i >> 10];
        row_ptr[i] = v;
        cursor[i]  = v;   // needed by the cursor fallback only
    }
    if (i == 0) row_ptr[N_NODES] = N_EDGES;
}

// ---------------------------------------------------------------------------
// k_scatter_rank: pos = row_ptr[dst] + rank  — NO atomics; the random write
// is fire-and-forget (no dependent use).
// ---------------------------------------------------------------------------
__global__ void k_scatter_rank(const int*   __restrict__ src,
                               const int*   __restrict__ dst,
                               const float* __restrict__ w,
                               const int*   __restrict__ rank,
                               const int*   __restrict__ row_ptr,
                               int2* __restrict__ pairs) {
    int i = blockIdx.x * blockDim.x + threadIdx.x;
    if (i >= N_EDGES) return;
    int d = dst[i];
    int pos = row_ptr[d] + rank[i];
    pairs[pos] = make_int2(src[i], __float_as_int(w[i]));
}

// fallback scatter with cursor atomics (R2 proven)
__global__ void k_scatter_cur(const int*   __restrict__ src,
                              const int*   __restrict__ dst,
                              const float* __restrict__ w,
                              int* __restrict__ cursor,
                              int2* __restrict__ pairs) {
    int i = blockIdx.x * blockDim.x + threadIdx.x;
    if (i >= N_EDGES) return;
    int d = dst[i];
    int pos = atomicAdd(&cursor[d], 1);
    pairs[pos] = make_int2(src[i], __float_as_int(w[i]));
}

// ---------------------------------------------------------------------------
// k_gather: one wave (64 lanes = EMB dims) per destination node.
//   nxt[d] = sum_{in-edges} w * x[src];  out[d] = (out[d] + nxt[d]) * scale
// 8-edge unroll via aligned 16B nontemporal pair loads; out traffic is
// nontemporal to keep the x-table resident in L2/L3.
// ---------------------------------------------------------------------------
__global__ __launch_bounds__(256) void k_gather(const int*  __restrict__ row_ptr,
                                                const int2* __restrict__ pairs,
                                                const float* __restrict__ x,
                                                float* __restrict__ nxt,
                                                float* __restrict__ out,
                                                float scale) {
    int wave = (blockIdx.x * blockDim.x + threadIdx.x) >> 6;
    int lane = threadIdx.x & 63;
    if (wave >= N_NODES) return;
    int beg = row_ptr[wave];
    int end = row_ptr[wave + 1];
    float acc = 0.f;
    int j = beg;

    const vi2* p2 = (const vi2*)pairs;

    // align j to even so 16B loads are aligned
    if ((j & 1) && j < end) {
        vi2 p = __builtin_nontemporal_load(&p2[j]);
        acc += __int_as_float(p.y) * x[(size_t)p.x * EMB + lane];
        ++j;
    }
    // 8 edges per iteration (4 x 16B = 8 pairs)
    for (; j + 7 < end; j += 8) {
        const vi4* pp = (const vi4*)(pairs + j);
        vi4 q0 = __builtin_nontemporal_load(pp + 0);
        vi4 q1 = __builtin_nontemporal_load(pp + 1);
        vi4 q2 = __builtin_nontemporal_load(pp + 2);
        vi4 q3 = __builtin_nontemporal_load(pp + 3);
        float a0 = x[(size_t)q0.x * EMB + lane];
        float a1 = x[(size_t)q0.z * EMB + lane];
        float a2 = x[(size_t)q1.x * EMB + lane];
        float a3 = x[(size_t)q1.z * EMB + lane];
        float a4 = x[(size_t)q2.x * EMB + lane];
        float a5 = x[(size_t)q2.z * EMB + lane];
        float a6 = x[(size_t)q3.x * EMB + lane];
        float a7 = x[(size_t)q3.z * EMB + lane];
        acc += __int_as_float(q0.y) * a0;
        acc += __int_as_float(q0.w) * a1;
        acc += __int_as_float(q1.y) * a2;
        acc += __int_as_float(q1.w) * a3;
        acc += __int_as_float(q2.y) * a4;
        acc += __int_as_float(q2.w) * a5;
        acc += __int_as_float(q3.y) * a6;
        acc += __int_as_float(q3.w) * a7;
    }
    // 2 edges per iteration
    for (; j + 1 < end; j += 2) {
        vi4 q = __builtin_nontemporal_load((const vi4*)(pairs + j));
        acc += __int_as_float(q.y) * x[(size_t)q.x * EMB + lane];
        acc += __int_as_float(q.w) * x[(size_t)q.z * EMB + lane];
    }
    if (j < end) {
        vi2 p = __builtin_nontemporal_load(&p2[j]);
        acc += __int_as_float(p.y) * x[(size_t)p.x * EMB + lane];
    }

    size_t o = (size_t)wave * EMB + lane;
    nxt[o] = acc;   // read next layer as x — keep cached
    float ov = __builtin_nontemporal_load(&out[o]);
    __builtin_nontemporal_store((ov + acc) * scale, &out[o]);
}

// ---------------------------------------------------------------------------
// Last-resort fallback (R1 atomic path)
// ---------------------------------------------------------------------------
__global__ void k_spmm(const int*   __restrict__ src,
                       const int*   __restrict__ dst,
                       const float* __restrict__ w,
                       const float* __restrict__ x,
                       float*       __restrict__ y) {
    long long t = (long long)blockIdx.x * blockDim.x + threadIdx.x;
    int e = (int)(t >> 4);
    if (e >= N_EDGES) return;
    int q = (int)(t & 15);
    int   s  = src[e];
    int   d  = dst[e];
    float we = w[e];
    const float4* xs = (const float4*)(x + (long long)s * EMB);
    float4 v = xs[q];
    float* yd = y + (long long)d * EMB + q * 4;
    atomicAdd(yd + 0, we * v.x);
    atomicAdd(yd + 1, we * v.y);
    atomicAdd(yd + 2, we * v.z);
    atomicAdd(yd + 3, we * v.w);
}

__global__ void k_acc(float4* __restrict__ out,
                      const float4* __restrict__ buf,
                      float scale) {
    int i = blockIdx.x * blockDim.x + threadIdx.x;
    const int total4 = N_NODES * EMB / 4;
    if (i >= total4) return;
    float4 o = out[i];
    float4 b = buf[i];
    o.x = (o.x + b.x) * scale;
    o.y = (o.y + b.y) * scale;
    o.z = (o.z + b.z) * scale;
    o.w = (o.w + b.w) * scale;
    out[i] = o;
}

extern "C" void kernel_launch(void* const* d_in, const int* in_sizes, int n_in,
                              void* d_out, int out_size, void* d_ws, size_t ws_size,
                              hipStream_t stream) {
    const float* user_emb = (const float*)d_in[0];
    const float* item_emb = (const float*)d_in[1];
    const float* edge_w   = (const float*)d_in[2];
    const int*   edge_src = (const int*)d_in[3];
    const int*   edge_dst = (const int*)d_in[4];
    float* out = (float*)d_out;

    const size_t feat_elems = (size_t)N_NODES * EMB;
    const size_t feat_bytes = feat_elems * sizeof(float);   // 38.4 MB

    // ---- workspace layout ----
    char* ws = (char*)d_ws;
    size_t off = 0;
    float* buf0 = (float*)(ws + off); off += feat_bytes;
    float* buf1 = (float*)(ws + off); off += feat_bytes;
    int* row_ptr = (int*)(ws + off);  off += ((size_t)(N_NODES + 1) * 4 + 63) / 64 * 64;
    int* cnt_cur = (int*)(ws + off);  off += ((size_t)N_NODES * 4 + 63) / 64 * 64;
    int* blk_sums = (int*)(ws + off); off += 1024;
    int* blk_offs = (int*)(ws + off); off += 1024;
    int2* pairs  = (int2*)(ws + off); off += (size_t)N_EDGES * 8;
    const size_t needed_csr = off;
    int* rank    = (int*)(ws + off);  off += (size_t)N_EDGES * 4;
    const size_t needed_rank = off;

    const int block = 256;
    const int total4 = (int)(feat_elems / 4);
    const int fgrid = (total4 + block - 1) / block;
    const int egrid = (N_EDGES + block - 1) / block;
    const int ngrid = (N_NODES + block - 1) / block;
    const int ggrid = (N_NODES + 3) / 4;   // 4 waves / 256-block

    if (ws_size >= needed_csr) {
        const bool use_rank = (ws_size >= needed_rank);
        (void)hipMemsetAsync(cnt_cur, 0, (size_t)N_NODES * 4, stream);

        k_init<<<fgrid, block, 0, stream>>>((const float4*)user_emb,
                                            (const float4*)item_emb,
                                            (float4*)out, (float4*)buf0);

        if (use_rank)
            k_count_rank<<<egrid, block, 0, stream>>>(edge_dst, cnt_cur, rank);
        else
            k_count<<<egrid, block, 0, stream>>>(edge_dst, cnt_cur);

        k_scan_local<<<N_SCAN_BLKS, SCAN_BLK, 0, stream>>>(cnt_cur, row_ptr, blk_sums);
        k_scan_blk<<<1, 256, 0, stream>>>(blk_sums, blk_offs);
        k_addoff<<<ngrid, block, 0, stream>>>(row_ptr, blk_offs, cnt_cur);

        if (use_rank)
            k_scatter_rank<<<egrid, block, 0, stream>>>(edge_src, edge_dst, edge_w,
                                                        rank, row_ptr, pairs);
        else
            k_scatter_cur<<<egrid, block, 0, stream>>>(edge_src, edge_dst, edge_w,
                                                       cnt_cur, pairs);

        float* cur = buf0;
        float* nxt = buf1;
        for (int layer = 0; layer < N_LAYERS; ++layer) {
            float scale = (layer == N_LAYERS - 1) ? (1.0f / (N_LAYERS + 1)) : 1.0f;
            k_gather<<<ggrid, block, 0, stream>>>(row_ptr, pairs, cur, nxt, out, scale);
            float* tmp = cur; cur = nxt; nxt = tmp;
        }
    } else {
        // atomic fallback
        k_init<<<fgrid, block, 0, stream>>>((const float4*)user_emb,
                                            (const float4*)item_emb,
                                            (float4*)out, (float4*)buf0);
        float* cur = buf0;
        float* nxt = buf1;
        for (int layer = 0; layer < N_LAYERS; ++layer) {
            (void)hipMemsetAsync(nxt, 0, feat_bytes, stream);
            long long threads = (long long)N_EDGES * 16;
            int grid = (int)((threads + block - 1) / block);
            k_spmm<<<grid, block, 0, stream>>>(edge_src, edge_dst, edge_w, cur, nxt);
            float scale = (layer == N_LAYERS - 1) ? (1.0f / (N_LAYERS + 1)) : 1.0f;
            k_acc<<<fgrid, block, 0, stream>>>((float4*)out, (const float4*)nxt, scale);
            float* tmp = cur; cur = nxt; nxt = tmp;
        }
    }
}

// Round 5
// 947.318 us; speedup vs baseline: 12.9541x; 1.0920x over previous
//
#include <hip/hip_runtime.h>
#include <hip/hip_fp16.h>

#define N_USERS 100000
#define N_ITEMS 50000
#define N_NODES 150000   // N_USERS + N_ITEMS
#define N_EDGES 4800000
#define EMB 64
#define N_LAYERS 3

#define SCAN_BLK 1024
#define N_SCAN_BLKS ((N_NODES + SCAN_BLK - 1) / SCAN_BLK)   // 147

typedef unsigned int u32;
// native vector type for __builtin_nontemporal_* (HIP vector classes rejected)
typedef u32 vu4 __attribute__((ext_vector_type(4)));

#define W_BITS 14
#define W_SCALE 16384.0f
#define W_INV   (1.0f / 16384.0f)
#define W_MASK  16383u

// ---------------------------------------------------------------------------
// k_init: out = ego (fp32) ; cur = ego as fp16 (internal layer storage).
// thread handles 4 dims.
// ---------------------------------------------------------------------------
__global__ void k_init(const float4* __restrict__ user,
                       const float4* __restrict__ item,
                       float4* __restrict__ out,
                       ushort4* __restrict__ cur) {
    int i = blockIdx.x * blockDim.x + threadIdx.x;
    const int total4 = N_NODES * EMB / 4;
    const int user4  = N_USERS * EMB / 4;
    if (i >= total4) return;
    float4 v = (i < user4) ? user[i] : item[i - user4];
    out[i] = v;
    ushort4 h;
    h.x = __half_as_ushort(__float2half_rn(v.x));
    h.y = __half_as_ushort(__float2half_rn(v.y));
    h.z = __half_as_ushort(__float2half_rn(v.z));
    h.w = __half_as_ushort(__float2half_rn(v.w));
    cur[i] = h;
}

// ---------------------------------------------------------------------------
// k_count_rank: histogram over dst + per-edge rank (atomic return is free).
// ---------------------------------------------------------------------------
__global__ void k_count_rank(const int* __restrict__ dst,
                             int* __restrict__ cnt,
                             int* __restrict__ rank) {
    int i = blockIdx.x * blockDim.x + threadIdx.x;
    if (i >= N_EDGES) return;
    rank[i] = atomicAdd(&cnt[dst[i]], 1);
}

// Per-block scan (Hillis-Steele in LDS) -> exclusive local values
__global__ void k_scan_local(const int* __restrict__ cnt,
                             int* __restrict__ row_ptr,
                             int* __restrict__ blk_sums) {
    __shared__ int tmp[SCAN_BLK];
    int tid = threadIdx.x;
    int gi  = blockIdx.x * SCAN_BLK + tid;
    int val = (gi < N_NODES) ? cnt[gi] : 0;
    tmp[tid] = val;
    __syncthreads();
    for (int off = 1; off < SCAN_BLK; off <<= 1) {
        int t = 0;
        if (tid >= off) t = tmp[tid - off];
        __syncthreads();
        if (tid >= off) tmp[tid] += t;
        __syncthreads();
    }
    if (gi < N_NODES) row_ptr[gi] = tmp[tid] - val;   // exclusive
    if (tid == SCAN_BLK - 1) blk_sums[blockIdx.x] = tmp[tid];
}

__global__ void k_scan_blk(const int* __restrict__ blk_sums,
                           int* __restrict__ blk_offs) {
    __shared__ int tmp[256];
    int tid = threadIdx.x;
    int val = (tid < N_SCAN_BLKS) ? blk_sums[tid] : 0;
    tmp[tid] = val;
    __syncthreads();
    for (int off = 1; off < 256; off <<= 1) {
        int t = 0;
        if (tid >= off) t = tmp[tid - off];
        __syncthreads();
        if (tid >= off) tmp[tid] += t;
        __syncthreads();
    }
    if (tid < N_SCAN_BLKS) blk_offs[tid] = tmp[tid] - val;  // exclusive
}

__global__ void k_addoff(int* __restrict__ row_ptr,
                         const int* __restrict__ blk_offs) {
    int i = blockIdx.x * blockDim.x + threadIdx.x;
    if (i < N_NODES) row_ptr[i] += blk_offs[i >> 10];
    if (i == 0) row_ptr[N_NODES] = N_EDGES;
}

// ---------------------------------------------------------------------------
// k_scatter_rank: pairs[row_ptr[dst]+rank] = (src << 14) | w_q14.  No atomics.
// w quantized to 14-bit fixed point (rel err 3e-5 — negligible vs threshold).
// ---------------------------------------------------------------------------
__global__ void k_scatter_rank(const int*   __restrict__ src,
                               const int*   __restrict__ dst,
                               const float* __restrict__ w,
                               const int*   __restrict__ rank,
                               const int*   __restrict__ row_ptr,
                               u32* __restrict__ pairs) {
    int i = blockIdx.x * blockDim.x + threadIdx.x;
    if (i >= N_EDGES) return;
    int d = dst[i];
    u32 wq = (u32)(w[i] * W_SCALE + 0.5f);
    if (wq > W_MASK) wq = W_MASK;
    u32 pk = ((u32)src[i] << W_BITS) | wq;
    pairs[row_ptr[d] + rank[i]] = pk;
}

// ---------------------------------------------------------------------------
// k_gather: one wave (64 lanes = EMB dims) per destination node.
//   acc = sum w * x[src]  (x in fp16, accumulate fp32)
//   out[d] = (out[d] + acc) * scale ; nxt[d] = fp16(acc) unless last layer
// 8 edges/iter via two aligned 16B nontemporal packed loads.
// ---------------------------------------------------------------------------
__global__ __launch_bounds__(256) void k_gather(const int* __restrict__ row_ptr,
                                                const u32* __restrict__ pairs,
                                                const __half* __restrict__ x,
                                                __half* __restrict__ nxt,
                                                float* __restrict__ out,
                                                float scale,
                                                int store_nxt) {
    int wave = (blockIdx.x * blockDim.x + threadIdx.x) >> 6;
    int lane = threadIdx.x & 63;
    if (wave >= N_NODES) return;
    int beg = row_ptr[wave];
    int end = row_ptr[wave + 1];
    const __half* xl = x + lane;
    float acc = 0.f;
    int j = beg;

    // scalar head until 16B-aligned
    for (; j < end && (j & 3); ++j) {
        u32 pk = pairs[j];
        float xv = __half2float(xl[(size_t)((pk >> W_BITS) << 6)]);
        acc = fmaf((float)(pk & W_MASK) * xv, W_INV, acc);
    }
    // 8 edges per iteration
    for (; j + 7 < end; j += 8) {
        const vu4* pp = (const vu4*)(pairs + j);
        vu4 a = __builtin_nontemporal_load(pp + 0);
        vu4 b = __builtin_nontemporal_load(pp + 1);
        float v0 = __half2float(xl[(size_t)((a.x >> W_BITS) << 6)]);
        float v1 = __half2float(xl[(size_t)((a.y >> W_BITS) << 6)]);
        float v2 = __half2float(xl[(size_t)((a.z >> W_BITS) << 6)]);
        float v3 = __half2float(xl[(size_t)((a.w >> W_BITS) << 6)]);
        float v4 = __half2float(xl[(size_t)((b.x >> W_BITS) << 6)]);
        float v5 = __half2float(xl[(size_t)((b.y >> W_BITS) << 6)]);
        float v6 = __half2float(xl[(size_t)((b.z >> W_BITS) << 6)]);
        float v7 = __half2float(xl[(size_t)((b.w >> W_BITS) << 6)]);
        acc = fmaf((float)(a.x & W_MASK) * v0, W_INV, acc);
        acc = fmaf((float)(a.y & W_MASK) * v1, W_INV, acc);
        acc = fmaf((float)(a.z & W_MASK) * v2, W_INV, acc);
        acc = fmaf((float)(a.w & W_MASK) * v3, W_INV, acc);
        acc = fmaf((float)(b.x & W_MASK) * v4, W_INV, acc);
        acc = fmaf((float)(b.y & W_MASK) * v5, W_INV, acc);
        acc = fmaf((float)(b.z & W_MASK) * v6, W_INV, acc);
        acc = fmaf((float)(b.w & W_MASK) * v7, W_INV, acc);
    }
    // 4 edges
    for (; j + 3 < end; j += 4) {
        vu4 a = __builtin_nontemporal_load((const vu4*)(pairs + j));
        float v0 = __half2float(xl[(size_t)((a.x >> W_BITS) << 6)]);
        float v1 = __half2float(xl[(size_t)((a.y >> W_BITS) << 6)]);
        float v2 = __half2float(xl[(size_t)((a.z >> W_BITS) << 6)]);
        float v3 = __half2float(xl[(size_t)((a.w >> W_BITS) << 6)]);
        acc = fmaf((float)(a.x & W_MASK) * v0, W_INV, acc);
        acc = fmaf((float)(a.y & W_MASK) * v1, W_INV, acc);
        acc = fmaf((float)(a.z & W_MASK) * v2, W_INV, acc);
        acc = fmaf((float)(a.w & W_MASK) * v3, W_INV, acc);
    }
    // scalar tail
    for (; j < end; ++j) {
        u32 pk = pairs[j];
        float xv = __half2float(xl[(size_t)((pk >> W_BITS) << 6)]);
        acc = fmaf((float)(pk & W_MASK) * xv, W_INV, acc);
    }

    size_t o = (size_t)wave * EMB + lane;
    if (store_nxt) nxt[o] = __float2half_rn(acc);
    float ov = __builtin_nontemporal_load(&out[o]);
    __builtin_nontemporal_store((ov + acc) * scale, &out[o]);
}

// ---------------------------------------------------------------------------
// Last-resort fallback (R1 atomic path, fp32 throughout)
// ---------------------------------------------------------------------------
__global__ void k_spmm(const int*   __restrict__ src,
                       const int*   __restrict__ dst,
                       const float* __restrict__ w,
                       const float* __restrict__ x,
                       float*       __restrict__ y) {
    long long t = (long long)blockIdx.x * blockDim.x + threadIdx.x;
    int e = (int)(t >> 4);
    if (e >= N_EDGES) return;
    int q = (int)(t & 15);
    int   s  = src[e];
    int   d  = dst[e];
    float we = w[e];
    const float4* xs = (const float4*)(x + (long long)s * EMB);
    float4 v = xs[q];
    float* yd = y + (long long)d * EMB + q * 4;
    atomicAdd(yd + 0, we * v.x);
    atomicAdd(yd + 1, we * v.y);
    atomicAdd(yd + 2, we * v.z);
    atomicAdd(yd + 3, we * v.w);
}

__global__ void k_init_f32(const float4* __restrict__ user,
                           const float4* __restrict__ item,
                           float4* __restrict__ out,
                           float4* __restrict__ cur) {
    int i = blockIdx.x * blockDim.x + threadIdx.x;
    const int total4 = N_NODES * EMB / 4;
    const int user4  = N_USERS * EMB / 4;
    if (i >= total4) return;
    float4 v = (i < user4) ? user[i] : item[i - user4];
    out[i] = v;
    cur[i] = v;
}

__global__ void k_acc(float4* __restrict__ out,
                      const float4* __restrict__ buf,
                      float scale) {
    int i = blockIdx.x * blockDim.x + threadIdx.x;
    const int total4 = N_NODES * EMB / 4;
    if (i >= total4) return;
    float4 o = out[i];
    float4 b = buf[i];
    o.x = (o.x + b.x) * scale;
    o.y = (o.y + b.y) * scale;
    o.z = (o.z + b.z) * scale;
    o.w = (o.w + b.w) * scale;
    out[i] = o;
}

extern "C" void kernel_launch(void* const* d_in, const int* in_sizes, int n_in,
                              void* d_out, int out_size, void* d_ws, size_t ws_size,
                              hipStream_t stream) {
    const float* user_emb = (const float*)d_in[0];
    const float* item_emb = (const float*)d_in[1];
    const float* edge_w   = (const float*)d_in[2];
    const int*   edge_src = (const int*)d_in[3];
    const int*   edge_dst = (const int*)d_in[4];
    float* out = (float*)d_out;

    const size_t feat_elems = (size_t)N_NODES * EMB;            // 9.6M
    const size_t feat_bytes_f32 = feat_elems * 4;               // 38.4 MB
    const size_t feat_bytes_f16 = feat_elems * 2;               // 19.2 MB

    // ---- workspace layout (fp16 path) ----
    char* ws = (char*)d_ws;
    size_t off = 0;
    __half* h0 = (__half*)(ws + off); off += feat_bytes_f16;
    __half* h1 = (__half*)(ws + off); off += feat_bytes_f16;
    int* row_ptr = (int*)(ws + off);  off += ((size_t)(N_NODES + 1) * 4 + 63) / 64 * 64;
    int* cnt     = (int*)(ws + off);  off += ((size_t)N_NODES * 4 + 63) / 64 * 64;
    int* blk_sums = (int*)(ws + off); off += 1024;
    int* blk_offs = (int*)(ws + off); off += 1024;
    u32* pairs = (u32*)(ws + off);    off += (size_t)N_EDGES * 4;
    int* rank  = (int*)(ws + off);    off += (size_t)N_EDGES * 4;
    const size_t needed = off;

    const int block = 256;
    const int total4 = (int)(feat_elems / 4);
    const int fgrid = (total4 + block - 1) / block;
    const int egrid = (N_EDGES + block - 1) / block;
    const int ngrid = (N_NODES + block - 1) / block;
    const int ggrid = (N_NODES + 3) / 4;   // 4 waves / 256-thread block

    if (ws_size >= needed) {
        (void)hipMemsetAsync(cnt, 0, (size_t)N_NODES * 4, stream);

        k_init<<<fgrid, block, 0, stream>>>((const float4*)user_emb,
                                            (const float4*)item_emb,
                                            (float4*)out, (ushort4*)h0);

        k_count_rank<<<egrid, block, 0, stream>>>(edge_dst, cnt, rank);
        k_scan_local<<<N_SCAN_BLKS, SCAN_BLK, 0, stream>>>(cnt, row_ptr, blk_sums);
        k_scan_blk<<<1, 256, 0, stream>>>(blk_sums, blk_offs);
        k_addoff<<<ngrid, block, 0, stream>>>(row_ptr, blk_offs);
        k_scatter_rank<<<egrid, block, 0, stream>>>(edge_src, edge_dst, edge_w,
                                                    rank, row_ptr, pairs);

        __half* cur = h0;
        __half* nxt = h1;
        for (int layer = 0; layer < N_LAYERS; ++layer) {
            int last = (layer == N_LAYERS - 1);
            float scale = last ? (1.0f / (N_LAYERS + 1)) : 1.0f;
            k_gather<<<ggrid, block, 0, stream>>>(row_ptr, pairs, cur, nxt, out,
                                                  scale, !last);
            __half* tmp = cur; cur = nxt; nxt = tmp;
        }
    } else {
        // atomic fallback (fp32) — needs 2 x 38.4 MB
        float* buf0 = (float*)d_ws;
        float* buf1 = buf0 + feat_elems;
        k_init_f32<<<fgrid, block, 0, stream>>>((const float4*)user_emb,
                                                (const float4*)item_emb,
                                                (float4*)out, (float4*)buf0);
        float* cur = buf0;
        float* nxt = buf1;
        for (int layer = 0; layer < N_LAYERS; ++layer) {
            (void)hipMemsetAsync(nxt, 0, feat_bytes_f32, stream);
            long long threads = (long long)N_EDGES * 16;
            int grid = (int)((threads + block - 1) / block);
            k_spmm<<<grid, block, 0, stream>>>(edge_src, edge_dst, edge_w, cur, nxt);
            float scale = (layer == N_LAYERS - 1) ? (1.0f / (N_LAYERS + 1)) : 1.0f;
            k_acc<<<fgrid, block, 0, stream>>>((float4*)out, (const float4*)nxt, scale);
            float* tmp = cur; cur = nxt; nxt = tmp;
        }
    }
}

// Round 6
// 929.679 us; speedup vs baseline: 13.1999x; 1.0190x over previous
//
#include <hip/hip_runtime.h>
#include <hip/hip_fp16.h>

#define N_USERS 100000
#define N_ITEMS 50000
#define N_NODES 150000   // N_USERS + N_ITEMS
#define N_EDGES 4800000
#define EMB 64
#define N_LAYERS 3

#define SCAN_BLK 1024
#define N_SCAN_BLKS ((N_NODES + SCAN_BLK - 1) / SCAN_BLK)   // 147

typedef unsigned int u32;
// native vector type for __builtin_nontemporal_* (HIP vector classes rejected)
typedef u32 vu4 __attribute__((ext_vector_type(4)));

#define W_BITS 14
#define W_SCALE 16384.0f
#define W_INV   (1.0f / 16384.0f)
#define W_MASK  16383u

// ---------------------------------------------------------------------------
// k_init: out = ego (fp32) ; cur = ego as fp16 (internal layer storage).
// ---------------------------------------------------------------------------
__global__ void k_init(const float4* __restrict__ user,
                       const float4* __restrict__ item,
                       float4* __restrict__ out,
                       ushort4* __restrict__ cur) {
    int i = blockIdx.x * blockDim.x + threadIdx.x;
    const int total4 = N_NODES * EMB / 4;
    const int user4  = N_USERS * EMB / 4;
    if (i >= total4) return;
    float4 v = (i < user4) ? user[i] : item[i - user4];
    out[i] = v;
    ushort4 h;
    h.x = __half_as_ushort(__float2half_rn(v.x));
    h.y = __half_as_ushort(__float2half_rn(v.y));
    h.z = __half_as_ushort(__float2half_rn(v.z));
    h.w = __half_as_ushort(__float2half_rn(v.w));
    cur[i] = h;
}

// ---------------------------------------------------------------------------
// k_count_rank4: 4 edges/thread -> 4 independent returning atomics in flight
// per lane-slot (ILP on the atomic latency chain). rank stored as int4.
// N_EDGES % 4 == 0.
// ---------------------------------------------------------------------------
__global__ void k_count_rank4(const int4* __restrict__ dst4,
                              int* __restrict__ cnt,
                              int4* __restrict__ rank4) {
    int i = blockIdx.x * blockDim.x + threadIdx.x;
    if (i >= N_EDGES / 4) return;
    int4 d = dst4[i];
    int4 r;
    r.x = atomicAdd(&cnt[d.x], 1);
    r.y = atomicAdd(&cnt[d.y], 1);
    r.z = atomicAdd(&cnt[d.z], 1);
    r.w = atomicAdd(&cnt[d.w], 1);
    rank4[i] = r;
}

// Per-block scan (Hillis-Steele in LDS) -> exclusive local values
__global__ void k_scan_local(const int* __restrict__ cnt,
                             int* __restrict__ row_ptr,
                             int* __restrict__ blk_sums) {
    __shared__ int tmp[SCAN_BLK];
    int tid = threadIdx.x;
    int gi  = blockIdx.x * SCAN_BLK + tid;
    int val = (gi < N_NODES) ? cnt[gi] : 0;
    tmp[tid] = val;
    __syncthreads();
    for (int off = 1; off < SCAN_BLK; off <<= 1) {
        int t = 0;
        if (tid >= off) t = tmp[tid - off];
        __syncthreads();
        if (tid >= off) tmp[tid] += t;
        __syncthreads();
    }
    if (gi < N_NODES) row_ptr[gi] = tmp[tid] - val;   // exclusive
    if (tid == SCAN_BLK - 1) blk_sums[blockIdx.x] = tmp[tid];
}

__global__ void k_scan_blk(const int* __restrict__ blk_sums,
                           int* __restrict__ blk_offs) {
    __shared__ int tmp[256];
    int tid = threadIdx.x;
    int val = (tid < N_SCAN_BLKS) ? blk_sums[tid] : 0;
    tmp[tid] = val;
    __syncthreads();
    for (int off = 1; off < 256; off <<= 1) {
        int t = 0;
        if (tid >= off) t = tmp[tid - off];
        __syncthreads();
        if (tid >= off) tmp[tid] += t;
        __syncthreads();
    }
    if (tid < N_SCAN_BLKS) blk_offs[tid] = tmp[tid] - val;  // exclusive
}

__global__ void k_addoff(int* __restrict__ row_ptr,
                         const int* __restrict__ blk_offs) {
    int i = blockIdx.x * blockDim.x + threadIdx.x;
    if (i < N_NODES) row_ptr[i] += blk_offs[i >> 10];
    if (i == 0) row_ptr[N_NODES] = N_EDGES;
}

// ---------------------------------------------------------------------------
// k_scatter_rank4: 4 edges/thread, all loads int4/float4-coalesced; 4
// independent fire-and-forget random stores in flight. No atomics.
// pairs[pos] = (src << 14) | w_q14.
// ---------------------------------------------------------------------------
__global__ void k_scatter_rank4(const int4*   __restrict__ src4,
                                const int4*   __restrict__ dst4,
                                const float4* __restrict__ w4,
                                const int4*   __restrict__ rank4,
                                const int*    __restrict__ row_ptr,
                                u32* __restrict__ pairs) {
    int i = blockIdx.x * blockDim.x + threadIdx.x;
    if (i >= N_EDGES / 4) return;
    int4   s = src4[i];
    int4   d = dst4[i];
    int4   r = rank4[i];
    float4 w = w4[i];

    int b0 = row_ptr[d.x];
    int b1 = row_ptr[d.y];
    int b2 = row_ptr[d.z];
    int b3 = row_ptr[d.w];

    u32 q0 = (u32)(w.x * W_SCALE + 0.5f); if (q0 > W_MASK) q0 = W_MASK;
    u32 q1 = (u32)(w.y * W_SCALE + 0.5f); if (q1 > W_MASK) q1 = W_MASK;
    u32 q2 = (u32)(w.z * W_SCALE + 0.5f); if (q2 > W_MASK) q2 = W_MASK;
    u32 q3 = (u32)(w.w * W_SCALE + 0.5f); if (q3 > W_MASK) q3 = W_MASK;

    pairs[b0 + r.x] = ((u32)s.x << W_BITS) | q0;
    pairs[b1 + r.y] = ((u32)s.y << W_BITS) | q1;
    pairs[b2 + r.z] = ((u32)s.z << W_BITS) | q2;
    pairs[b3 + r.w] = ((u32)s.w << W_BITS) | q3;
}

// ---------------------------------------------------------------------------
// k_gather: one wave (64 lanes = EMB dims) per destination node.
//   acc = sum w * x[src]  (x in fp16, accumulate fp32)
//   out[d] = (out[d] + acc) * scale ; nxt[d] = fp16(acc) unless last layer
// ---------------------------------------------------------------------------
__global__ __launch_bounds__(256) void k_gather(const int* __restrict__ row_ptr,
                                                const u32* __restrict__ pairs,
                                                const __half* __restrict__ x,
                                                __half* __restrict__ nxt,
                                                float* __restrict__ out,
                                                float scale,
                                                int store_nxt) {
    int wave = (blockIdx.x * blockDim.x + threadIdx.x) >> 6;
    int lane = threadIdx.x & 63;
    if (wave >= N_NODES) return;
    int beg = row_ptr[wave];
    int end = row_ptr[wave + 1];
    const __half* xl = x + lane;
    float acc = 0.f;
    int j = beg;

    // scalar head until 16B-aligned
    for (; j < end && (j & 3); ++j) {
        u32 pk = pairs[j];
        float xv = __half2float(xl[(size_t)((pk >> W_BITS) << 6)]);
        acc = fmaf((float)(pk & W_MASK) * xv, W_INV, acc);
    }
    // 8 edges per iteration
    for (; j + 7 < end; j += 8) {
        const vu4* pp = (const vu4*)(pairs + j);
        vu4 a = __builtin_nontemporal_load(pp + 0);
        vu4 b = __builtin_nontemporal_load(pp + 1);
        float v0 = __half2float(xl[(size_t)((a.x >> W_BITS) << 6)]);
        float v1 = __half2float(xl[(size_t)((a.y >> W_BITS) << 6)]);
        float v2 = __half2float(xl[(size_t)((a.z >> W_BITS) << 6)]);
        float v3 = __half2float(xl[(size_t)((a.w >> W_BITS) << 6)]);
        float v4 = __half2float(xl[(size_t)((b.x >> W_BITS) << 6)]);
        float v5 = __half2float(xl[(size_t)((b.y >> W_BITS) << 6)]);
        float v6 = __half2float(xl[(size_t)((b.z >> W_BITS) << 6)]);
        float v7 = __half2float(xl[(size_t)((b.w >> W_BITS) << 6)]);
        acc = fmaf((float)(a.x & W_MASK) * v0, W_INV, acc);
        acc = fmaf((float)(a.y & W_MASK) * v1, W_INV, acc);
        acc = fmaf((float)(a.z & W_MASK) * v2, W_INV, acc);
        acc = fmaf((float)(a.w & W_MASK) * v3, W_INV, acc);
        acc = fmaf((float)(b.x & W_MASK) * v4, W_INV, acc);
        acc = fmaf((float)(b.y & W_MASK) * v5, W_INV, acc);
        acc = fmaf((float)(b.z & W_MASK) * v6, W_INV, acc);
        acc = fmaf((float)(b.w & W_MASK) * v7, W_INV, acc);
    }
    // 4 edges
    for (; j + 3 < end; j += 4) {
        vu4 a = __builtin_nontemporal_load((const vu4*)(pairs + j));
        float v0 = __half2float(xl[(size_t)((a.x >> W_BITS) << 6)]);
        float v1 = __half2float(xl[(size_t)((a.y >> W_BITS) << 6)]);
        float v2 = __half2float(xl[(size_t)((a.z >> W_BITS) << 6)]);
        float v3 = __half2float(xl[(size_t)((a.w >> W_BITS) << 6)]);
        acc = fmaf((float)(a.x & W_MASK) * v0, W_INV, acc);
        acc = fmaf((float)(a.y & W_MASK) * v1, W_INV, acc);
        acc = fmaf((float)(a.z & W_MASK) * v2, W_INV, acc);
        acc = fmaf((float)(a.w & W_MASK) * v3, W_INV, acc);
    }
    // scalar tail
    for (; j < end; ++j) {
        u32 pk = pairs[j];
        float xv = __half2float(xl[(size_t)((pk >> W_BITS) << 6)]);
        acc = fmaf((float)(pk & W_MASK) * xv, W_INV, acc);
    }

    size_t o = (size_t)wave * EMB + lane;
    if (store_nxt) nxt[o] = __float2half_rn(acc);
    float ov = __builtin_nontemporal_load(&out[o]);
    __builtin_nontemporal_store((ov + acc) * scale, &out[o]);
}

// ---------------------------------------------------------------------------
// Last-resort fallback (R1 atomic path, fp32 throughout)
// ---------------------------------------------------------------------------
__global__ void k_spmm(const int*   __restrict__ src,
                       const int*   __restrict__ dst,
                       const float* __restrict__ w,
                       const float* __restrict__ x,
                       float*       __restrict__ y) {
    long long t = (long long)blockIdx.x * blockDim.x + threadIdx.x;
    int e = (int)(t >> 4);
    if (e >= N_EDGES) return;
    int q = (int)(t & 15);
    int   s  = src[e];
    int   d  = dst[e];
    float we = w[e];
    const float4* xs = (const float4*)(x + (long long)s * EMB);
    float4 v = xs[q];
    float* yd = y + (long long)d * EMB + q * 4;
    atomicAdd(yd + 0, we * v.x);
    atomicAdd(yd + 1, we * v.y);
    atomicAdd(yd + 2, we * v.z);
    atomicAdd(yd + 3, we * v.w);
}

__global__ void k_init_f32(const float4* __restrict__ user,
                           const float4* __restrict__ item,
                           float4* __restrict__ out,
                           float4* __restrict__ cur) {
    int i = blockIdx.x * blockDim.x + threadIdx.x;
    const int total4 = N_NODES * EMB / 4;
    const int user4  = N_USERS * EMB / 4;
    if (i >= total4) return;
    float4 v = (i < user4) ? user[i] : item[i - user4];
    out[i] = v;
    cur[i] = v;
}

__global__ void k_acc(float4* __restrict__ out,
                      const float4* __restrict__ buf,
                      float scale) {
    int i = blockIdx.x * blockDim.x + threadIdx.x;
    const int total4 = N_NODES * EMB / 4;
    if (i >= total4) return;
    float4 o = out[i];
    float4 b = buf[i];
    o.x = (o.x + b.x) * scale;
    o.y = (o.y + b.y) * scale;
    o.z = (o.z + b.z) * scale;
    o.w = (o.w + b.w) * scale;
    out[i] = o;
}

extern "C" void kernel_launch(void* const* d_in, const int* in_sizes, int n_in,
                              void* d_out, int out_size, void* d_ws, size_t ws_size,
                              hipStream_t stream) {
    const float* user_emb = (const float*)d_in[0];
    const float* item_emb = (const float*)d_in[1];
    const float* edge_w   = (const float*)d_in[2];
    const int*   edge_src = (const int*)d_in[3];
    const int*   edge_dst = (const int*)d_in[4];
    float* out = (float*)d_out;

    const size_t feat_elems = (size_t)N_NODES * EMB;            // 9.6M
    const size_t feat_bytes_f32 = feat_elems * 4;               // 38.4 MB
    const size_t feat_bytes_f16 = feat_elems * 2;               // 19.2 MB

    // ---- workspace layout (fp16 path) ----
    char* ws = (char*)d_ws;
    size_t off = 0;
    __half* h0 = (__half*)(ws + off); off += feat_bytes_f16;
    __half* h1 = (__half*)(ws + off); off += feat_bytes_f16;
    int* row_ptr = (int*)(ws + off);  off += ((size_t)(N_NODES + 1) * 4 + 63) / 64 * 64;
    int* cnt     = (int*)(ws + off);  off += ((size_t)N_NODES * 4 + 63) / 64 * 64;
    int* blk_sums = (int*)(ws + off); off += 1024;
    int* blk_offs = (int*)(ws + off); off += 1024;
    u32* pairs = (u32*)(ws + off);    off += (size_t)N_EDGES * 4;
    int* rank  = (int*)(ws + off);    off += (size_t)N_EDGES * 4;
    const size_t needed = off;

    const int block = 256;
    const int total4 = (int)(feat_elems / 4);
    const int fgrid = (total4 + block - 1) / block;
    const int e4grid = (N_EDGES / 4 + block - 1) / block;
    const int ngrid = (N_NODES + block - 1) / block;
    const int ggrid = (N_NODES + 3) / 4;   // 4 waves / 256-thread block

    if (ws_size >= needed) {
        (void)hipMemsetAsync(cnt, 0, (size_t)N_NODES * 4, stream);

        k_init<<<fgrid, block, 0, stream>>>((const float4*)user_emb,
                                            (const float4*)item_emb,
                                            (float4*)out, (ushort4*)h0);

        k_count_rank4<<<e4grid, block, 0, stream>>>((const int4*)edge_dst, cnt,
                                                    (int4*)rank);
        k_scan_local<<<N_SCAN_BLKS, SCAN_BLK, 0, stream>>>(cnt, row_ptr, blk_sums);
        k_scan_blk<<<1, 256, 0, stream>>>(blk_sums, blk_offs);
        k_addoff<<<ngrid, block, 0, stream>>>(row_ptr, blk_offs);
        k_scatter_rank4<<<e4grid, block, 0, stream>>>((const int4*)edge_src,
                                                      (const int4*)edge_dst,
                                                      (const float4*)edge_w,
                                                      (const int4*)rank,
                                                      row_ptr, pairs);

        __half* cur = h0;
        __half* nxt = h1;
        for (int layer = 0; layer < N_LAYERS; ++layer) {
            int last = (layer == N_LAYERS - 1);
            float scale = last ? (1.0f / (N_LAYERS + 1)) : 1.0f;
            k_gather<<<ggrid, block, 0, stream>>>(row_ptr, pairs, cur, nxt, out,
                                                  scale, !last);
            __half* tmp = cur; cur = nxt; nxt = tmp;
        }
    } else {
        // atomic fallback (fp32) — needs 2 x 38.4 MB
        float* buf0 = (float*)d_ws;
        float* buf1 = buf0 + feat_elems;
        k_init_f32<<<fgrid, block, 0, stream>>>((const float4*)user_emb,
                                                (const float4*)item_emb,
                                                (float4*)out, (float4*)buf0);
        float* cur = buf0;
        float* nxt = buf1;
        const int egrid = (N_EDGES + block - 1) / block;
        for (int layer = 0; layer < N_LAYERS; ++layer) {
            (void)hipMemsetAsync(nxt, 0, feat_bytes_f32, stream);
            long long threads = (long long)N_EDGES * 16;
            int grid = (int)((threads + block - 1) / block);
            k_spmm<<<grid, block, 0, stream>>>(edge_src, edge_dst, edge_w, cur, nxt);
            float scale = (layer == N_LAYERS - 1) ? (1.0f / (N_LAYERS + 1)) : 1.0f;
            k_acc<<<fgrid, block, 0, stream>>>((float4*)out, (const float4*)nxt, scale);
            float* tmp = cur; cur = nxt; nxt = tmp;
        }
        (void)egrid;
    }
}

// Round 7
// 687.500 us; speedup vs baseline: 17.8497x; 1.3523x over previous
//
#include <hip/hip_runtime.h>
#include <hip/hip_fp16.h>

#define N_USERS 100000
#define N_ITEMS 50000
#define N_NODES 150000   // N_USERS + N_ITEMS
#define N_EDGES 4800000
#define EMB 64
#define N_LAYERS 3

// ---- bucketed counting-sort CSR build ----
#define NBKT 256
#define NPB  586                 // nodes per bucket: 586*256 = 150016 >= 150000
#define NREP 8                   // cursor replicas (shorter same-address atomic chains)
#define SUBCAP 2624              // per-(bucket,replica) capacity; mean 2344, +5.8 sigma
#define CAP (NREP * SUBCAP)      // 20992 slots per bucket

typedef unsigned int u32;
typedef unsigned short u16;
typedef u32 vu4 __attribute__((ext_vector_type(4)));

#define W_BITS 14
#define W_SCALE 16384.0f
#define W_INV   (1.0f / 16384.0f)
#define W_MASK  16383u

// ---------------------------------------------------------------------------
// k_init: out = ego (fp32) ; cur = ego as fp16 (internal layer storage).
// ---------------------------------------------------------------------------
__global__ void k_init(const float4* __restrict__ user,
                       const float4* __restrict__ item,
                       float4* __restrict__ out,
                       ushort4* __restrict__ cur) {
    int i = blockIdx.x * blockDim.x + threadIdx.x;
    const int total4 = N_NODES * EMB / 4;
    const int user4  = N_USERS * EMB / 4;
    if (i >= total4) return;
    float4 v = (i < user4) ? user[i] : item[i - user4];
    out[i] = v;
    ushort4 h;
    h.x = __half_as_ushort(__float2half_rn(v.x));
    h.y = __half_as_ushort(__float2half_rn(v.y));
    h.z = __half_as_ushort(__float2half_rn(v.z));
    h.w = __half_as_ushort(__float2half_rn(v.w));
    cur[i] = h;
}

// ---------------------------------------------------------------------------
// k_p1: bucket edges by dst/NPB. LDS histogram assigns free local ranks;
// ONE global atomic per (block,bucket) instead of one per edge.
// 8 edges/thread, 2048 edges/block, grid 2344.
// ---------------------------------------------------------------------------
__global__ __launch_bounds__(256) void k_p1(const int4*   __restrict__ src4,
                                            const int4*   __restrict__ dst4,
                                            const float4* __restrict__ w4,
                                            int* __restrict__ cursor,   // [NREP*NBKT]
                                            u32* __restrict__ pk_arr,   // [NBKT*CAP]
                                            u16* __restrict__ ld_arr) { // [NBKT*CAP]
    __shared__ int hist[NBKT];
    __shared__ int base[NBKT];
    int tid = threadIdx.x;
    hist[tid] = 0;
    __syncthreads();

    int g0 = blockIdx.x * 512 + tid * 2;    // int4 index; edges e = g0*4 .. g0*4+7
    bool act = (g0 < N_EDGES / 4);          // N_EDGES%8==0 -> whole-thread guard

    u32 pk[8];
    u32 meta[8];
    if (act) {
        int4 d0 = dst4[g0], d1 = dst4[g0 + 1];
        int4 s0 = src4[g0], s1 = src4[g0 + 1];
        float4 f0 = w4[g0], f1 = w4[g0 + 1];
        int   ds[8] = {d0.x, d0.y, d0.z, d0.w, d1.x, d1.y, d1.z, d1.w};
        int   ss[8] = {s0.x, s0.y, s0.z, s0.w, s1.x, s1.y, s1.z, s1.w};
        float wf[8] = {f0.x, f0.y, f0.z, f0.w, f1.x, f1.y, f1.z, f1.w};
        #pragma unroll
        for (int k = 0; k < 8; ++k) {
            u32 d  = (u32)ds[k];
            u32 b  = d / NPB;               // const-div -> magic multiply
            u32 ld = d - b * NPB;           // local dst, < 586
            int r  = atomicAdd(&hist[b], 1);  // LDS atomic, returns local rank
            u32 wq = (u32)(wf[k] * W_SCALE + 0.5f);
            if (wq > W_MASK) wq = W_MASK;
            pk[k]   = ((u32)ss[k] << W_BITS) | wq;
            meta[k] = ((u32)r << 18) | (b << 10) | ld;  // r<2048(11b), b(8b), ld(10b)
        }
    }
    __syncthreads();

    int rep = blockIdx.x & (NREP - 1);
    int h = hist[tid];
    if (h > 0) base[tid] = atomicAdd(&cursor[rep * NBKT + tid], h);
    __syncthreads();

    if (act) {
        #pragma unroll
        for (int k = 0; k < 8; ++k) {
            u32 b  = (meta[k] >> 10) & 255u;
            u32 r  = meta[k] >> 18;
            u32 ld = meta[k] & 1023u;
            int pos = base[b] + (int)r;
            if (pos < SUBCAP) {             // statistical impossibility; guard anyway
                size_t slot = (size_t)b * CAP + (size_t)rep * SUBCAP + pos;
                pk_arr[slot] = pk[k];
                ld_arr[slot] = (u16)ld;
            }
        }
    }
}

// ---------------------------------------------------------------------------
// k_scan256: exclusive scan of per-bucket totals -> bucket bases.
// ---------------------------------------------------------------------------
__global__ void k_scan256(const int* __restrict__ cursor,
                          int* __restrict__ bkt_base,
                          int* __restrict__ row_ptr) {
    __shared__ int tmp[NBKT];
    int tid = threadIdx.x;
    int tot = 0;
    for (int r = 0; r < NREP; ++r) tot += cursor[r * NBKT + tid];
    tmp[tid] = tot;
    __syncthreads();
    for (int off = 1; off < NBKT; off <<= 1) {
        int t = 0;
        if (tid >= off) t = tmp[tid - off];
        __syncthreads();
        if (tid >= off) tmp[tid] += t;
        __syncthreads();
    }
    bkt_base[tid] = tmp[tid] - tot;   // exclusive
    if (tid == 0) row_ptr[N_NODES] = N_EDGES;
}

// ---------------------------------------------------------------------------
// k_p2: one block per bucket. LDS histogram over <=586 local nodes, LDS scan,
// emit row_ptr, scatter pairs into final dense CSR (LDS cursor atomics,
// global writes confined to this bucket's ~75 KB window -> L2-local).
// ---------------------------------------------------------------------------
__global__ __launch_bounds__(1024) void k_p2(const int* __restrict__ cursor,
                                             const int* __restrict__ bkt_base,
                                             const u32* __restrict__ pk_arr,
                                             const u16* __restrict__ ld_arr,
                                             int* __restrict__ row_ptr,
                                             u32* __restrict__ pairs) {
    __shared__ int hist[1024];
    __shared__ int cur[NPB];
    int b = blockIdx.x;
    int tid = threadIdx.x;
    hist[tid] = 0;
    __syncthreads();

    int lo = b * NPB;
    int nb = N_NODES - lo; if (nb > NPB) nb = NPB;

    int n[NREP];
    #pragma unroll
    for (int r = 0; r < NREP; ++r) {
        int c = cursor[r * NBKT + b];
        n[r] = (c > SUBCAP) ? SUBCAP : c;   // match what was actually written
    }

    // pass A: local-dst histogram
    for (int r = 0; r < NREP; ++r) {
        const u16* p = ld_arr + (size_t)b * CAP + (size_t)r * SUBCAP;
        for (int i = tid; i < n[r]; i += 1024)
            atomicAdd(&hist[p[i]], 1);
    }
    __syncthreads();

    // inclusive scan over 1024 entries (only [0,nb) nonzero)
    int val = hist[tid];
    for (int off = 1; off < 1024; off <<= 1) {
        int t = 0;
        if (tid >= off) t = hist[tid - off];
        __syncthreads();
        if (tid >= off) hist[tid] += t;
        __syncthreads();
    }
    int excl = hist[tid] - val;
    int gbase = bkt_base[b];
    if (tid < nb) {
        row_ptr[lo + tid] = gbase + excl;
        cur[tid] = excl;
    }
    __syncthreads();

    // pass B: scatter into final CSR
    for (int r = 0; r < NREP; ++r) {
        const u16* p = ld_arr + (size_t)b * CAP + (size_t)r * SUBCAP;
        const u32* q = pk_arr + (size_t)b * CAP + (size_t)r * SUBCAP;
        for (int i = tid; i < n[r]; i += 1024) {
            int ld  = p[i];
            int pos = atomicAdd(&cur[ld], 1);   // LDS atomic
            pairs[gbase + pos] = q[i];
        }
    }
}

// ---------------------------------------------------------------------------
// k_gather: one wave (64 lanes = EMB dims) per destination node. (unchanged)
// ---------------------------------------------------------------------------
__global__ __launch_bounds__(256) void k_gather(const int* __restrict__ row_ptr,
                                                const u32* __restrict__ pairs,
                                                const __half* __restrict__ x,
                                                __half* __restrict__ nxt,
                                                float* __restrict__ out,
                                                float scale,
                                                int store_nxt) {
    int wave = (blockIdx.x * blockDim.x + threadIdx.x) >> 6;
    int lane = threadIdx.x & 63;
    if (wave >= N_NODES) return;
    int beg = row_ptr[wave];
    int end = row_ptr[wave + 1];
    const __half* xl = x + lane;
    float acc = 0.f;
    int j = beg;

    for (; j < end && (j & 3); ++j) {
        u32 pk = pairs[j];
        float xv = __half2float(xl[(size_t)((pk >> W_BITS) << 6)]);
        acc = fmaf((float)(pk & W_MASK) * xv, W_INV, acc);
    }
    for (; j + 7 < end; j += 8) {
        const vu4* pp = (const vu4*)(pairs + j);
        vu4 a = __builtin_nontemporal_load(pp + 0);
        vu4 b = __builtin_nontemporal_load(pp + 1);
        float v0 = __half2float(xl[(size_t)((a.x >> W_BITS) << 6)]);
        float v1 = __half2float(xl[(size_t)((a.y >> W_BITS) << 6)]);
        float v2 = __half2float(xl[(size_t)((a.z >> W_BITS) << 6)]);
        float v3 = __half2float(xl[(size_t)((a.w >> W_BITS) << 6)]);
        float v4 = __half2float(xl[(size_t)((b.x >> W_BITS) << 6)]);
        float v5 = __half2float(xl[(size_t)((b.y >> W_BITS) << 6)]);
        float v6 = __half2float(xl[(size_t)((b.z >> W_BITS) << 6)]);
        float v7 = __half2float(xl[(size_t)((b.w >> W_BITS) << 6)]);
        acc = fmaf((float)(a.x & W_MASK) * v0, W_INV, acc);
        acc = fmaf((float)(a.y & W_MASK) * v1, W_INV, acc);
        acc = fmaf((float)(a.z & W_MASK) * v2, W_INV, acc);
        acc = fmaf((float)(a.w & W_MASK) * v3, W_INV, acc);
        acc = fmaf((float)(b.x & W_MASK) * v4, W_INV, acc);
        acc = fmaf((float)(b.y & W_MASK) * v5, W_INV, acc);
        acc = fmaf((float)(b.z & W_MASK) * v6, W_INV, acc);
        acc = fmaf((float)(b.w & W_MASK) * v7, W_INV, acc);
    }
    for (; j + 3 < end; j += 4) {
        vu4 a = __builtin_nontemporal_load((const vu4*)(pairs + j));
        float v0 = __half2float(xl[(size_t)((a.x >> W_BITS) << 6)]);
        float v1 = __half2float(xl[(size_t)((a.y >> W_BITS) << 6)]);
        float v2 = __half2float(xl[(size_t)((a.z >> W_BITS) << 6)]);
        float v3 = __half2float(xl[(size_t)((a.w >> W_BITS) << 6)]);
        acc = fmaf((float)(a.x & W_MASK) * v0, W_INV, acc);
        acc = fmaf((float)(a.y & W_MASK) * v1, W_INV, acc);
        acc = fmaf((float)(a.z & W_MASK) * v2, W_INV, acc);
        acc = fmaf((float)(a.w & W_MASK) * v3, W_INV, acc);
    }
    for (; j < end; ++j) {
        u32 pk = pairs[j];
        float xv = __half2float(xl[(size_t)((pk >> W_BITS) << 6)]);
        acc = fmaf((float)(pk & W_MASK) * xv, W_INV, acc);
    }

    size_t o = (size_t)wave * EMB + lane;
    if (store_nxt) nxt[o] = __float2half_rn(acc);
    float ov = __builtin_nontemporal_load(&out[o]);
    __builtin_nontemporal_store((ov + acc) * scale, &out[o]);
}

// ---------------------------------------------------------------------------
// Fallback (R1 atomic path, fp32) if workspace is too small
// ---------------------------------------------------------------------------
__global__ void k_spmm(const int*   __restrict__ src,
                       const int*   __restrict__ dst,
                       const float* __restrict__ w,
                       const float* __restrict__ x,
                       float*       __restrict__ y) {
    long long t = (long long)blockIdx.x * blockDim.x + threadIdx.x;
    int e = (int)(t >> 4);
    if (e >= N_EDGES) return;
    int q = (int)(t & 15);
    int   s  = src[e];
    int   d  = dst[e];
    float we = w[e];
    const float4* xs = (const float4*)(x + (long long)s * EMB);
    float4 v = xs[q];
    float* yd = y + (long long)d * EMB + q * 4;
    atomicAdd(yd + 0, we * v.x);
    atomicAdd(yd + 1, we * v.y);
    atomicAdd(yd + 2, we * v.z);
    atomicAdd(yd + 3, we * v.w);
}

__global__ void k_init_f32(const float4* __restrict__ user,
                           const float4* __restrict__ item,
                           float4* __restrict__ out,
                           float4* __restrict__ cur) {
    int i = blockIdx.x * blockDim.x + threadIdx.x;
    const int total4 = N_NODES * EMB / 4;
    const int user4  = N_USERS * EMB / 4;
    if (i >= total4) return;
    float4 v = (i < user4) ? user[i] : item[i - user4];
    out[i] = v;
    cur[i] = v;
}

__global__ void k_acc(float4* __restrict__ out,
                      const float4* __restrict__ buf,
                      float scale) {
    int i = blockIdx.x * blockDim.x + threadIdx.x;
    const int total4 = N_NODES * EMB / 4;
    if (i >= total4) return;
    float4 o = out[i];
    float4 b = buf[i];
    o.x = (o.x + b.x) * scale;
    o.y = (o.y + b.y) * scale;
    o.z = (o.z + b.z) * scale;
    o.w = (o.w + b.w) * scale;
    out[i] = o;
}

extern "C" void kernel_launch(void* const* d_in, const int* in_sizes, int n_in,
                              void* d_out, int out_size, void* d_ws, size_t ws_size,
                              hipStream_t stream) {
    const float* user_emb = (const float*)d_in[0];
    const float* item_emb = (const float*)d_in[1];
    const float* edge_w   = (const float*)d_in[2];
    const int*   edge_src = (const int*)d_in[3];
    const int*   edge_dst = (const int*)d_in[4];
    float* out = (float*)d_out;

    const size_t feat_elems = (size_t)N_NODES * EMB;            // 9.6M
    const size_t feat_bytes_f32 = feat_elems * 4;               // 38.4 MB
    const size_t feat_bytes_f16 = feat_elems * 2;               // 19.2 MB

    // ---- workspace layout ----
    char* ws = (char*)d_ws;
    size_t off = 0;
    __half* h0 = (__half*)(ws + off); off += feat_bytes_f16;
    __half* h1 = (__half*)(ws + off); off += feat_bytes_f16;
    int* row_ptr  = (int*)(ws + off); off += ((size_t)(N_NODES + 1) * 4 + 63) / 64 * 64;
    int* cursor   = (int*)(ws + off); off += (size_t)NREP * NBKT * 4;
    int* bkt_base = (int*)(ws + off); off += (size_t)NBKT * 4;
    u32* pk_arr = (u32*)(ws + off);   off += (size_t)NBKT * CAP * 4;   // 21.5 MB
    u16* ld_arr = (u16*)(ws + off);   off += (size_t)NBKT * CAP * 2;   // 10.7 MB
    u32* pairs  = (u32*)(ws + off);   off += (size_t)N_EDGES * 4;      // 19.2 MB
    const size_t needed = off;

    const int block = 256;
    const int total4 = (int)(feat_elems / 4);
    const int fgrid = (total4 + block - 1) / block;
    const int p1grid = (N_EDGES / 8 + block - 1) / block;   // 2344
    const int ggrid = (N_NODES + 3) / 4;                    // 4 waves / 256-thread block

    if (ws_size >= needed) {
        (void)hipMemsetAsync(cursor, 0, (size_t)NREP * NBKT * 4, stream);

        k_init<<<fgrid, block, 0, stream>>>((const float4*)user_emb,
                                            (const float4*)item_emb,
                                            (float4*)out, (ushort4*)h0);

        k_p1<<<p1grid, block, 0, stream>>>((const int4*)edge_src,
                                           (const int4*)edge_dst,
                                           (const float4*)edge_w,
                                           cursor, pk_arr, ld_arr);
        k_scan256<<<1, NBKT, 0, stream>>>(cursor, bkt_base, row_ptr);
        k_p2<<<NBKT, 1024, 0, stream>>>(cursor, bkt_base, pk_arr, ld_arr,
                                        row_ptr, pairs);

        __half* cur = h0;
        __half* nxt = h1;
        for (int layer = 0; layer < N_LAYERS; ++layer) {
            int last = (layer == N_LAYERS - 1);
            float scale = last ? (1.0f / (N_LAYERS + 1)) : 1.0f;
            k_gather<<<ggrid, block, 0, stream>>>(row_ptr, pairs, cur, nxt, out,
                                                  scale, !last);
            __half* tmp = cur; cur = nxt; nxt = tmp;
        }
    } else {
        // atomic fallback (fp32) — needs 2 x 38.4 MB
        float* buf0 = (float*)d_ws;
        float* buf1 = buf0 + feat_elems;
        k_init_f32<<<fgrid, block, 0, stream>>>((const float4*)user_emb,
                                                (const float4*)item_emb,
                                                (float4*)out, (float4*)buf0);
        float* cur = buf0;
        float* nxt = buf1;
        for (int layer = 0; layer < N_LAYERS; ++layer) {
            (void)hipMemsetAsync(nxt, 0, feat_bytes_f32, stream);
            long long threads = (long long)N_EDGES * 16;
            int grid = (int)((threads + block - 1) / block);
            k_spmm<<<grid, block, 0, stream>>>(edge_src, edge_dst, edge_w, cur, nxt);
            float scale = (layer == N_LAYERS - 1) ? (1.0f / (N_LAYERS + 1)) : 1.0f;
            k_acc<<<fgrid, block, 0, stream>>>((float4*)out, (const float4*)nxt, scale);
            float* tmp = cur; cur = nxt; nxt = tmp;
        }
    }
}

// Round 8
// 655.869 us; speedup vs baseline: 18.7105x; 1.0482x over previous
//
#include <hip/hip_runtime.h>
#include <hip/hip_fp16.h>

#define N_USERS 100000
#define N_ITEMS 50000
#define N_NODES 150000   // N_USERS + N_ITEMS
#define N_EDGES 4800000
#define EMB 64
#define N_LAYERS 3

// ---- bucketed counting-sort CSR build ----
#define NBKT 256
#define NPB  586                 // nodes per bucket: 586*256 = 150016 >= 150000
#define NREP 8                   // cursor replicas
#define SUBCAP 2624              // per-(bucket,replica) capacity
#define CAP (NREP * SUBCAP)      // 20992 slots per bucket

typedef unsigned int u32;
typedef unsigned short u16;
typedef u32 vu4 __attribute__((ext_vector_type(4)));

#define W_BITS 14
#define W_SCALE 16384.0f
#define W_INV   (1.0f / 16384.0f)
#define W_MASK  16383u

// ---------------------------------------------------------------------------
// k_init: cur = ego as fp16 (internal layer storage). out written by k_fin.
// ---------------------------------------------------------------------------
__global__ void k_init(const float4* __restrict__ user,
                       const float4* __restrict__ item,
                       ushort4* __restrict__ cur) {
    int i = blockIdx.x * blockDim.x + threadIdx.x;
    const int total4 = N_NODES * EMB / 4;
    const int user4  = N_USERS * EMB / 4;
    if (i >= total4) return;
    float4 v = (i < user4) ? user[i] : item[i - user4];
    ushort4 h;
    h.x = __half_as_ushort(__float2half_rn(v.x));
    h.y = __half_as_ushort(__float2half_rn(v.y));
    h.z = __half_as_ushort(__float2half_rn(v.z));
    h.w = __half_as_ushort(__float2half_rn(v.w));
    cur[i] = h;
}

// ---------------------------------------------------------------------------
// k_p1: bucket edges by dst/NPB. LDS histogram assigns free local ranks;
// ONE global atomic per (block,bucket). 8 edges/thread.
// ---------------------------------------------------------------------------
__global__ __launch_bounds__(256) void k_p1(const int4*   __restrict__ src4,
                                            const int4*   __restrict__ dst4,
                                            const float4* __restrict__ w4,
                                            int* __restrict__ cursor,   // [NREP*NBKT]
                                            u32* __restrict__ pk_arr,   // [NBKT*CAP]
                                            u16* __restrict__ ld_arr) { // [NBKT*CAP]
    __shared__ int hist[NBKT];
    __shared__ int base[NBKT];
    int tid = threadIdx.x;
    hist[tid] = 0;
    __syncthreads();

    int g0 = blockIdx.x * 512 + tid * 2;
    bool act = (g0 < N_EDGES / 4);

    u32 pk[8];
    u32 meta[8];
    if (act) {
        int4 d0 = dst4[g0], d1 = dst4[g0 + 1];
        int4 s0 = src4[g0], s1 = src4[g0 + 1];
        float4 f0 = w4[g0], f1 = w4[g0 + 1];
        int   ds[8] = {d0.x, d0.y, d0.z, d0.w, d1.x, d1.y, d1.z, d1.w};
        int   ss[8] = {s0.x, s0.y, s0.z, s0.w, s1.x, s1.y, s1.z, s1.w};
        float wf[8] = {f0.x, f0.y, f0.z, f0.w, f1.x, f1.y, f1.z, f1.w};
        #pragma unroll
        for (int k = 0; k < 8; ++k) {
            u32 d  = (u32)ds[k];
            u32 b  = d / NPB;
            u32 ld = d - b * NPB;
            int r  = atomicAdd(&hist[b], 1);
            u32 wq = (u32)(wf[k] * W_SCALE + 0.5f);
            if (wq > W_MASK) wq = W_MASK;
            pk[k]   = ((u32)ss[k] << W_BITS) | wq;
            meta[k] = ((u32)r << 18) | (b << 10) | ld;
        }
    }
    __syncthreads();

    int rep = blockIdx.x & (NREP - 1);
    int h = hist[tid];
    if (h > 0) base[tid] = atomicAdd(&cursor[rep * NBKT + tid], h);
    __syncthreads();

    if (act) {
        #pragma unroll
        for (int k = 0; k < 8; ++k) {
            u32 b  = (meta[k] >> 10) & 255u;
            u32 r  = meta[k] >> 18;
            u32 ld = meta[k] & 1023u;
            int pos = base[b] + (int)r;
            if (pos < SUBCAP) {
                size_t slot = (size_t)b * CAP + (size_t)rep * SUBCAP + pos;
                pk_arr[slot] = pk[k];
                ld_arr[slot] = (u16)ld;
            }
        }
    }
}

// ---------------------------------------------------------------------------
// k_scan256: exclusive scan of per-bucket totals -> bucket bases.
// ---------------------------------------------------------------------------
__global__ void k_scan256(const int* __restrict__ cursor,
                          int* __restrict__ bkt_base,
                          int* __restrict__ row_ptr) {
    __shared__ int tmp[NBKT];
    int tid = threadIdx.x;
    int tot = 0;
    for (int r = 0; r < NREP; ++r) tot += cursor[r * NBKT + tid];
    tmp[tid] = tot;
    __syncthreads();
    for (int off = 1; off < NBKT; off <<= 1) {
        int t = 0;
        if (tid >= off) t = tmp[tid - off];
        __syncthreads();
        if (tid >= off) tmp[tid] += t;
        __syncthreads();
    }
    bkt_base[tid] = tmp[tid] - tot;
    if (tid == 0) row_ptr[N_NODES] = N_EDGES;
}

// ---------------------------------------------------------------------------
// k_p2: one block per bucket. LDS histogram + scan, emit row_ptr, scatter
// pairs into final dense CSR (LDS atomics, L2-local global writes).
// ---------------------------------------------------------------------------
__global__ __launch_bounds__(1024) void k_p2(const int* __restrict__ cursor,
                                             const int* __restrict__ bkt_base,
                                             const u32* __restrict__ pk_arr,
                                             const u16* __restrict__ ld_arr,
                                             int* __restrict__ row_ptr,
                                             u32* __restrict__ pairs) {
    __shared__ int hist[1024];
    __shared__ int cur[NPB];
    int b = blockIdx.x;
    int tid = threadIdx.x;
    hist[tid] = 0;
    __syncthreads();

    int lo = b * NPB;
    int nb = N_NODES - lo; if (nb > NPB) nb = NPB;

    int n[NREP];
    #pragma unroll
    for (int r = 0; r < NREP; ++r) {
        int c = cursor[r * NBKT + b];
        n[r] = (c > SUBCAP) ? SUBCAP : c;
    }

    for (int r = 0; r < NREP; ++r) {
        const u16* p = ld_arr + (size_t)b * CAP + (size_t)r * SUBCAP;
        for (int i = tid; i < n[r]; i += 1024)
            atomicAdd(&hist[p[i]], 1);
    }
    __syncthreads();

    int val = hist[tid];
    for (int off = 1; off < 1024; off <<= 1) {
        int t = 0;
        if (tid >= off) t = hist[tid - off];
        __syncthreads();
        if (tid >= off) hist[tid] += t;
        __syncthreads();
    }
    int excl = hist[tid] - val;
    int gbase = bkt_base[b];
    if (tid < nb) {
        row_ptr[lo + tid] = gbase + excl;
        cur[tid] = excl;
    }
    __syncthreads();

    for (int r = 0; r < NREP; ++r) {
        const u16* p = ld_arr + (size_t)b * CAP + (size_t)r * SUBCAP;
        const u32* q = pk_arr + (size_t)b * CAP + (size_t)r * SUBCAP;
        for (int i = tid; i < n[r]; i += 1024) {
            int ld  = p[i];
            int pos = atomicAdd(&cur[ld], 1);
            pairs[gbase + pos] = q[i];
        }
    }
}

// ---------------------------------------------------------------------------
// k_gather: one wave per dst node; 2 dims/lane (lane m -> dims 2m,2m+1).
// Lanes 0-31 process even edges, lanes 32-63 odd edges -> each x-row load is
// a full-width dword load serving 2 edges/instruction. Combined via shfl.
// Writes only nxt (fp16); out is accumulated later by k_fin.
// ---------------------------------------------------------------------------
__global__ __launch_bounds__(256) void k_gather(const int* __restrict__ row_ptr,
                                                const u32* __restrict__ pairs,
                                                const __half* __restrict__ x,
                                                __half* __restrict__ nxt) {
    int wave = (blockIdx.x * blockDim.x + threadIdx.x) >> 6;
    int lane = threadIdx.x & 63;
    if (wave >= N_NODES) return;
    int beg = row_ptr[wave];
    int end = row_ptr[wave + 1];

    const bool hi = lane >= 32;     // odd-edge half
    const int  m  = lane & 31;      // dim pair index
    const u32* xw = (const u32*)x;  // half2 view of x
    float ax = 0.f, ay = 0.f;
    int j = beg;

    // head: single edges until 16B-aligned (both halves same row; hi weight=0)
    for (; j < end && (j & 3); ++j) {
        u32 pk = pairs[j];
        u32 xb = xw[(size_t)(pk >> W_BITS) * 32 + m];
        float2 xv = __half22float2(*(__half2*)&xb);
        float wf = hi ? 0.f : (float)(pk & W_MASK) * W_INV;
        ax = fmaf(wf, xv.x, ax);
        ay = fmaf(wf, xv.y, ay);
    }
    // 8 edges per iteration: 2 broadcast pair-loads + 4 dword x-loads
    for (; j + 7 < end; j += 8) {
        const vu4* pp = (const vu4*)(pairs + j);
        vu4 a = __builtin_nontemporal_load(pp + 0);
        vu4 b = __builtin_nontemporal_load(pp + 1);
        u32 p0 = hi ? a.y : a.x;
        u32 p1 = hi ? a.w : a.z;
        u32 p2 = hi ? b.y : b.x;
        u32 p3 = hi ? b.w : b.z;
        u32 x0 = xw[(size_t)(p0 >> W_BITS) * 32 + m];
        u32 x1 = xw[(size_t)(p1 >> W_BITS) * 32 + m];
        u32 x2 = xw[(size_t)(p2 >> W_BITS) * 32 + m];
        u32 x3 = xw[(size_t)(p3 >> W_BITS) * 32 + m];
        float w0 = (float)(p0 & W_MASK) * W_INV;
        float w1 = (float)(p1 & W_MASK) * W_INV;
        float w2 = (float)(p2 & W_MASK) * W_INV;
        float w3 = (float)(p3 & W_MASK) * W_INV;
        float2 v0 = __half22float2(*(__half2*)&x0);
        float2 v1 = __half22float2(*(__half2*)&x1);
        float2 v2 = __half22float2(*(__half2*)&x2);
        float2 v3 = __half22float2(*(__half2*)&x3);
        ax = fmaf(w0, v0.x, ax); ay = fmaf(w0, v0.y, ay);
        ax = fmaf(w1, v1.x, ax); ay = fmaf(w1, v1.y, ay);
        ax = fmaf(w2, v2.x, ax); ay = fmaf(w2, v2.y, ay);
        ax = fmaf(w3, v3.x, ax); ay = fmaf(w3, v3.y, ay);
    }
    // 4 edges
    for (; j + 3 < end; j += 4) {
        vu4 a = __builtin_nontemporal_load((const vu4*)(pairs + j));
        u32 p0 = hi ? a.y : a.x;
        u32 p1 = hi ? a.w : a.z;
        u32 x0 = xw[(size_t)(p0 >> W_BITS) * 32 + m];
        u32 x1 = xw[(size_t)(p1 >> W_BITS) * 32 + m];
        float w0 = (float)(p0 & W_MASK) * W_INV;
        float w1 = (float)(p1 & W_MASK) * W_INV;
        float2 v0 = __half22float2(*(__half2*)&x0);
        float2 v1 = __half22float2(*(__half2*)&x1);
        ax = fmaf(w0, v0.x, ax); ay = fmaf(w0, v0.y, ay);
        ax = fmaf(w1, v1.x, ax); ay = fmaf(w1, v1.y, ay);
    }
    // tail: single edges
    for (; j < end; ++j) {
        u32 pk = pairs[j];
        u32 xb = xw[(size_t)(pk >> W_BITS) * 32 + m];
        float2 xv = __half22float2(*(__half2*)&xb);
        float wf = hi ? 0.f : (float)(pk & W_MASK) * W_INV;
        ax = fmaf(wf, xv.x, ax);
        ay = fmaf(wf, xv.y, ay);
    }

    // combine even-edge (lanes 0-31) and odd-edge (lanes 32-63) partial sums
    ax += __shfl_down(ax, 32);
    ay += __shfl_down(ay, 32);
    if (!hi) {
        __half2 hv = __floats2half2_rn(ax, ay);
        ((__half2*)nxt)[(size_t)wave * 32 + m] = hv;
    }
}

// ---------------------------------------------------------------------------
// k_fin: out = (ego + e1 + e2 + e3) * 0.25   (streaming, float4 x half4)
// ---------------------------------------------------------------------------
__global__ void k_fin(const float4* __restrict__ user,
                      const float4* __restrict__ item,
                      const ushort4* __restrict__ e1,
                      const ushort4* __restrict__ e2,
                      const ushort4* __restrict__ e3,
                      float4* __restrict__ out) {
    int i = blockIdx.x * blockDim.x + threadIdx.x;
    const int total4 = N_NODES * EMB / 4;
    const int user4  = N_USERS * EMB / 4;
    if (i >= total4) return;
    float4 v = (i < user4) ? user[i] : item[i - user4];
    ushort4 a = e1[i], b = e2[i], c = e3[i];
    v.x = (v.x + __half2float(__ushort_as_half(a.x))
              + __half2float(__ushort_as_half(b.x))
              + __half2float(__ushort_as_half(c.x))) * 0.25f;
    v.y = (v.y + __half2float(__ushort_as_half(a.y))
              + __half2float(__ushort_as_half(b.y))
              + __half2float(__ushort_as_half(c.y))) * 0.25f;
    v.z = (v.z + __half2float(__ushort_as_half(a.z))
              + __half2float(__ushort_as_half(b.z))
              + __half2float(__ushort_as_half(c.z))) * 0.25f;
    v.w = (v.w + __half2float(__ushort_as_half(a.w))
              + __half2float(__ushort_as_half(b.w))
              + __half2float(__ushort_as_half(c.w))) * 0.25f;
    __builtin_nontemporal_store(v.x, &((float*)out)[4 * (size_t)i + 0]);
    __builtin_nontemporal_store(v.y, &((float*)out)[4 * (size_t)i + 1]);
    __builtin_nontemporal_store(v.z, &((float*)out)[4 * (size_t)i + 2]);
    __builtin_nontemporal_store(v.w, &((float*)out)[4 * (size_t)i + 3]);
}

// ---------------------------------------------------------------------------
// Fallback (R1 atomic path, fp32) if workspace is too small
// ---------------------------------------------------------------------------
__global__ void k_spmm(const int*   __restrict__ src,
                       const int*   __restrict__ dst,
                       const float* __restrict__ w,
                       const float* __restrict__ x,
                       float*       __restrict__ y) {
    long long t = (long long)blockIdx.x * blockDim.x + threadIdx.x;
    int e = (int)(t >> 4);
    if (e >= N_EDGES) return;
    int q = (int)(t & 15);
    int   s  = src[e];
    int   d  = dst[e];
    float we = w[e];
    const float4* xs = (const float4*)(x + (long long)s * EMB);
    float4 v = xs[q];
    float* yd = y + (long long)d * EMB + q * 4;
    atomicAdd(yd + 0, we * v.x);
    atomicAdd(yd + 1, we * v.y);
    atomicAdd(yd + 2, we * v.z);
    atomicAdd(yd + 3, we * v.w);
}

__global__ void k_init_f32(const float4* __restrict__ user,
                           const float4* __restrict__ item,
                           float4* __restrict__ out,
                           float4* __restrict__ cur) {
    int i = blockIdx.x * blockDim.x + threadIdx.x;
    const int total4 = N_NODES * EMB / 4;
    const int user4  = N_USERS * EMB / 4;
    if (i >= total4) return;
    float4 v = (i < user4) ? user[i] : item[i - user4];
    out[i] = v;
    cur[i] = v;
}

__global__ void k_acc(float4* __restrict__ out,
                      const float4* __restrict__ buf,
                      float scale) {
    int i = blockIdx.x * blockDim.x + threadIdx.x;
    const int total4 = N_NODES * EMB / 4;
    if (i >= total4) return;
    float4 o = out[i];
    float4 b = buf[i];
    o.x = (o.x + b.x) * scale;
    o.y = (o.y + b.y) * scale;
    o.z = (o.z + b.z) * scale;
    o.w = (o.w + b.w) * scale;
    out[i] = o;
}

extern "C" void kernel_launch(void* const* d_in, const int* in_sizes, int n_in,
                              void* d_out, int out_size, void* d_ws, size_t ws_size,
                              hipStream_t stream) {
    const float* user_emb = (const float*)d_in[0];
    const float* item_emb = (const float*)d_in[1];
    const float* edge_w   = (const float*)d_in[2];
    const int*   edge_src = (const int*)d_in[3];
    const int*   edge_dst = (const int*)d_in[4];
    float* out = (float*)d_out;

    const size_t feat_elems = (size_t)N_NODES * EMB;            // 9.6M
    const size_t feat_bytes_f32 = feat_elems * 4;               // 38.4 MB
    const size_t feat_bytes_f16 = feat_elems * 2;               // 19.2 MB

    // ---- workspace layout ----
    char* ws = (char*)d_ws;
    size_t off = 0;
    __half* h0 = (__half*)(ws + off); off += feat_bytes_f16;
    __half* h1 = (__half*)(ws + off); off += feat_bytes_f16;
    __half* h2 = (__half*)(ws + off); off += feat_bytes_f16;
    __half* h3 = (__half*)(ws + off); off += feat_bytes_f16;
    int* row_ptr  = (int*)(ws + off); off += ((size_t)(N_NODES + 1) * 4 + 63) / 64 * 64;
    int* cursor   = (int*)(ws + off); off += (size_t)NREP * NBKT * 4;
    int* bkt_base = (int*)(ws + off); off += (size_t)NBKT * 4;
    u32* pk_arr = (u32*)(ws + off);   off += (size_t)NBKT * CAP * 4;   // 21.5 MB
    u16* ld_arr = (u16*)(ws + off);   off += (size_t)NBKT * CAP * 2;   // 10.7 MB
    u32* pairs  = (u32*)(ws + off);   off += (size_t)N_EDGES * 4;      // 19.2 MB
    const size_t needed = off;

    const int block = 256;
    const int total4 = (int)(feat_elems / 4);
    const int fgrid = (total4 + block - 1) / block;
    const int p1grid = (N_EDGES / 8 + block - 1) / block;   // 2344
    const int ggrid = (N_NODES + 3) / 4;                    // 4 waves / 256-thread block

    if (ws_size >= needed) {
        (void)hipMemsetAsync(cursor, 0, (size_t)NREP * NBKT * 4, stream);

        k_init<<<fgrid, block, 0, stream>>>((const float4*)user_emb,
                                            (const float4*)item_emb,
                                            (ushort4*)h0);

        k_p1<<<p1grid, block, 0, stream>>>((const int4*)edge_src,
                                           (const int4*)edge_dst,
                                           (const float4*)edge_w,
                                           cursor, pk_arr, ld_arr);
        k_scan256<<<1, NBKT, 0, stream>>>(cursor, bkt_base, row_ptr);
        k_p2<<<NBKT, 1024, 0, stream>>>(cursor, bkt_base, pk_arr, ld_arr,
                                        row_ptr, pairs);

        __half* bufs[4] = {h0, h1, h2, h3};
        for (int layer = 0; layer < N_LAYERS; ++layer)
            k_gather<<<ggrid, block, 0, stream>>>(row_ptr, pairs,
                                                  bufs[layer], bufs[layer + 1]);

        k_fin<<<fgrid, block, 0, stream>>>((const float4*)user_emb,
                                           (const float4*)item_emb,
                                           (const ushort4*)h1,
                                           (const ushort4*)h2,
                                           (const ushort4*)h3,
                                           (float4*)out);
    } else {
        // atomic fallback (fp32) — needs 2 x 38.4 MB
        float* buf0 = (float*)d_ws;
        float* buf1 = buf0 + feat_elems;
        k_init_f32<<<fgrid, block, 0, stream>>>((const float4*)user_emb,
                                                (const float4*)item_emb,
                                                (float4*)out, (float4*)buf0);
        float* cur = buf0;
        float* nxt = buf1;
        for (int layer = 0; layer < N_LAYERS; ++layer) {
            (void)hipMemsetAsync(nxt, 0, feat_bytes_f32, stream);
            long long threads = (long long)N_EDGES * 16;
            int grid = (int)((threads + block - 1) / block);
            k_spmm<<<grid, block, 0, stream>>>(edge_src, edge_dst, edge_w, cur, nxt);
            float scale = (layer == N_LAYERS - 1) ? (1.0f / (N_LAYERS + 1)) : 1.0f;
            k_acc<<<fgrid, block, 0, stream>>>((float4*)out, (const float4*)nxt, scale);
            float* tmp = cur; cur = nxt; nxt = tmp;
        }
    }
}

// Round 10
// 609.437 us; speedup vs baseline: 20.1360x; 1.0762x over previous
//
#include <hip/hip_runtime.h>
#include <hip/hip_fp16.h>

#define N_USERS 100000
#define N_ITEMS 50000
#define N_NODES 150000   // N_USERS + N_ITEMS
#define N_EDGES 4800000
#define EMB 64
#define N_LAYERS 3

// ---- bucketed counting-sort CSR build ----
#define NBKT 256
#define NPB  586                 // nodes per bucket: 586*256 = 150016 >= 150000
#define NREP 8                   // cursor replicas
#define SUBCAP 2624              // per-(bucket,replica) capacity
#define CAP (NREP * SUBCAP)      // 20992 slots per bucket

typedef unsigned int u32;
typedef unsigned short u16;
typedef u32 vu4 __attribute__((ext_vector_type(4)));
typedef u32 vu2 __attribute__((ext_vector_type(2)));

#define W_BITS 14
#define W_SCALE 16384.0f
#define W_INV   (1.0f / 16384.0f)
#define W_MASK  16383u

// decode a u32 holding two packed halves -> float2 (no address-of on vector
// elements; compiles to two v_cvt_f32_f16)
__device__ __forceinline__ float2 h2f(u32 v) {
    float2 r;
    r.x = __half2float(__ushort_as_half((u16)(v & 0xffffu)));
    r.y = __half2float(__ushort_as_half((u16)(v >> 16)));
    return r;
}

// ---------------------------------------------------------------------------
// k_init: cur = ego as fp16 (internal layer storage). out written by k_fin.
// ---------------------------------------------------------------------------
__global__ void k_init(const float4* __restrict__ user,
                       const float4* __restrict__ item,
                       ushort4* __restrict__ cur) {
    int i = blockIdx.x * blockDim.x + threadIdx.x;
    const int total4 = N_NODES * EMB / 4;
    const int user4  = N_USERS * EMB / 4;
    if (i >= total4) return;
    float4 v = (i < user4) ? user[i] : item[i - user4];
    ushort4 h;
    h.x = __half_as_ushort(__float2half_rn(v.x));
    h.y = __half_as_ushort(__float2half_rn(v.y));
    h.z = __half_as_ushort(__float2half_rn(v.z));
    h.w = __half_as_ushort(__float2half_rn(v.w));
    cur[i] = h;
}

// ---------------------------------------------------------------------------
// k_p1: bucket edges by dst/NPB. LDS histogram assigns free local ranks;
// ONE global atomic per (block,bucket). 8 edges/thread.
// ---------------------------------------------------------------------------
__global__ __launch_bounds__(256) void k_p1(const int4*   __restrict__ src4,
                                            const int4*   __restrict__ dst4,
                                            const float4* __restrict__ w4,
                                            int* __restrict__ cursor,   // [NREP*NBKT]
                                            u32* __restrict__ pk_arr,   // [NBKT*CAP]
                                            u16* __restrict__ ld_arr) { // [NBKT*CAP]
    __shared__ int hist[NBKT];
    __shared__ int base[NBKT];
    int tid = threadIdx.x;
    hist[tid] = 0;
    __syncthreads();

    int g0 = blockIdx.x * 512 + tid * 2;
    bool act = (g0 < N_EDGES / 4);

    u32 pk[8];
    u32 meta[8];
    if (act) {
        int4 d0 = dst4[g0], d1 = dst4[g0 + 1];
        int4 s0 = src4[g0], s1 = src4[g0 + 1];
        float4 f0 = w4[g0], f1 = w4[g0 + 1];
        int   ds[8] = {d0.x, d0.y, d0.z, d0.w, d1.x, d1.y, d1.z, d1.w};
        int   ss[8] = {s0.x, s0.y, s0.z, s0.w, s1.x, s1.y, s1.z, s1.w};
        float wf[8] = {f0.x, f0.y, f0.z, f0.w, f1.x, f1.y, f1.z, f1.w};
        #pragma unroll
        for (int k = 0; k < 8; ++k) {
            u32 d  = (u32)ds[k];
            u32 b  = d / NPB;
            u32 ld = d - b * NPB;
            int r  = atomicAdd(&hist[b], 1);
            u32 wq = (u32)(wf[k] * W_SCALE + 0.5f);
            if (wq > W_MASK) wq = W_MASK;
            pk[k]   = ((u32)ss[k] << W_BITS) | wq;
            meta[k] = ((u32)r << 18) | (b << 10) | ld;
        }
    }
    __syncthreads();

    int rep = blockIdx.x & (NREP - 1);
    int h = hist[tid];
    if (h > 0) base[tid] = atomicAdd(&cursor[rep * NBKT + tid], h);
    __syncthreads();

    if (act) {
        #pragma unroll
        for (int k = 0; k < 8; ++k) {
            u32 b  = (meta[k] >> 10) & 255u;
            u32 r  = meta[k] >> 18;
            u32 ld = meta[k] & 1023u;
            int pos = base[b] + (int)r;
            if (pos < SUBCAP) {
                size_t slot = (size_t)b * CAP + (size_t)rep * SUBCAP + pos;
                pk_arr[slot] = pk[k];
                ld_arr[slot] = (u16)ld;
            }
        }
    }
}

// ---------------------------------------------------------------------------
// k_scan256: exclusive scan of per-bucket totals -> bucket bases.
// ---------------------------------------------------------------------------
__global__ void k_scan256(const int* __restrict__ cursor,
                          int* __restrict__ bkt_base,
                          int* __restrict__ row_ptr) {
    __shared__ int tmp[NBKT];
    int tid = threadIdx.x;
    int tot = 0;
    for (int r = 0; r < NREP; ++r) tot += cursor[r * NBKT + tid];
    tmp[tid] = tot;
    __syncthreads();
    for (int off = 1; off < NBKT; off <<= 1) {
        int t = 0;
        if (tid >= off) t = tmp[tid - off];
        __syncthreads();
        if (tid >= off) tmp[tid] += t;
        __syncthreads();
    }
    bkt_base[tid] = tmp[tid] - tot;
    if (tid == 0) row_ptr[N_NODES] = N_EDGES;
}

// ---------------------------------------------------------------------------
// k_p2: one block per bucket. LDS histogram + scan, emit row_ptr, scatter
// pairs into final dense CSR (LDS atomics, L2-local global writes).
// ---------------------------------------------------------------------------
__global__ __launch_bounds__(1024) void k_p2(const int* __restrict__ cursor,
                                             const int* __restrict__ bkt_base,
                                             const u32* __restrict__ pk_arr,
                                             const u16* __restrict__ ld_arr,
                                             int* __restrict__ row_ptr,
                                             u32* __restrict__ pairs) {
    __shared__ int hist[1024];
    __shared__ int cur[NPB];
    int b = blockIdx.x;
    int tid = threadIdx.x;
    hist[tid] = 0;
    __syncthreads();

    int lo = b * NPB;
    int nb = N_NODES - lo; if (nb > NPB) nb = NPB;

    int n[NREP];
    #pragma unroll
    for (int r = 0; r < NREP; ++r) {
        int c = cursor[r * NBKT + b];
        n[r] = (c > SUBCAP) ? SUBCAP : c;
    }

    for (int r = 0; r < NREP; ++r) {
        const u16* p = ld_arr + (size_t)b * CAP + (size_t)r * SUBCAP;
        for (int i = tid; i < n[r]; i += 1024)
            atomicAdd(&hist[p[i]], 1);
    }
    __syncthreads();

    int val = hist[tid];
    for (int off = 1; off < 1024; off <<= 1) {
        int t = 0;
        if (tid >= off) t = hist[tid - off];
        __syncthreads();
        if (tid >= off) hist[tid] += t;
        __syncthreads();
    }
    int excl = hist[tid] - val;
    int gbase = bkt_base[b];
    if (tid < nb) {
        row_ptr[lo + tid] = gbase + excl;
        cur[tid] = excl;
    }
    __syncthreads();

    for (int r = 0; r < NREP; ++r) {
        const u16* p = ld_arr + (size_t)b * CAP + (size_t)r * SUBCAP;
        const u32* q = pk_arr + (size_t)b * CAP + (size_t)r * SUBCAP;
        for (int i = tid; i < n[r]; i += 1024) {
            int ld  = p[i];
            int pos = atomicAdd(&cur[ld], 1);
            pairs[gbase + pos] = q[i];
        }
    }
}

// ---------------------------------------------------------------------------
// k_gather: one wave per dst node; lane = g*16+m; group g (4 groups) owns
// its edges, lane covers dims [4m,4m+4) via one 8B dwordx2 load per edge.
// 16-edge body: 1 pair-load instr (per-group segment) + 4 x-load instrs
// (each serving 4 rows = 512B/wave). Cross-group combine: shfl_xor(16),(32).
// ---------------------------------------------------------------------------
__global__ __launch_bounds__(256) void k_gather(const int* __restrict__ row_ptr,
                                                const u32* __restrict__ pairs,
                                                const __half* __restrict__ x,
                                                __half* __restrict__ nxt) {
    int wave = (blockIdx.x * blockDim.x + threadIdx.x) >> 6;
    int lane = threadIdx.x & 63;
    if (wave >= N_NODES) return;
    int beg = row_ptr[wave];
    int end = row_ptr[wave + 1];

    const int g = lane >> 4;        // edge group 0..3
    const int m = lane & 15;        // dim quad: dims [4m, 4m+4)
    const vu2* xq = (const vu2*)x;  // 4-half (8B) view; row r quad m at r*16+m
    float ax = 0.f, ay = 0.f, az = 0.f, aw = 0.f;
    int j = beg;

    // scalar head until j%4==0 (only group 0 accumulates; others weight 0)
    for (; j < end && (j & 3); ++j) {
        u32 pk = pairs[j];
        vu2 xv = xq[(size_t)(pk >> W_BITS) * 16 + m];
        float wf = (g == 0) ? (float)(pk & W_MASK) * W_INV : 0.f;
        float2 lo = h2f(xv.x);
        float2 hi = h2f(xv.y);
        ax = fmaf(wf, lo.x, ax); ay = fmaf(wf, lo.y, ay);
        az = fmaf(wf, hi.x, az); aw = fmaf(wf, hi.y, aw);
    }
    // 16-edge bodies: group g handles edges j+4g .. j+4g+3
    for (; j + 15 < end; j += 16) {
        vu4 p = __builtin_nontemporal_load((const vu4*)(pairs + j + 4 * g));
        vu2 x0 = xq[(size_t)(p.x >> W_BITS) * 16 + m];
        vu2 x1 = xq[(size_t)(p.y >> W_BITS) * 16 + m];
        vu2 x2 = xq[(size_t)(p.z >> W_BITS) * 16 + m];
        vu2 x3 = xq[(size_t)(p.w >> W_BITS) * 16 + m];
        float w0 = (float)(p.x & W_MASK) * W_INV;
        float w1 = (float)(p.y & W_MASK) * W_INV;
        float w2 = (float)(p.z & W_MASK) * W_INV;
        float w3 = (float)(p.w & W_MASK) * W_INV;
        float2 a0 = h2f(x0.x), b0 = h2f(x0.y);
        float2 a1 = h2f(x1.x), b1 = h2f(x1.y);
        float2 a2 = h2f(x2.x), b2 = h2f(x2.y);
        float2 a3 = h2f(x3.x), b3 = h2f(x3.y);
        ax = fmaf(w0, a0.x, ax); ay = fmaf(w0, a0.y, ay);
        az = fmaf(w0, b0.x, az); aw = fmaf(w0, b0.y, aw);
        ax = fmaf(w1, a1.x, ax); ay = fmaf(w1, a1.y, ay);
        az = fmaf(w1, b1.x, az); aw = fmaf(w1, b1.y, aw);
        ax = fmaf(w2, a2.x, ax); ay = fmaf(w2, a2.y, ay);
        az = fmaf(w2, b2.x, az); aw = fmaf(w2, b2.y, aw);
        ax = fmaf(w3, a3.x, ax); ay = fmaf(w3, a3.y, ay);
        az = fmaf(w3, b3.x, az); aw = fmaf(w3, b3.y, aw);
    }
    // 4-edge chunks: one edge per group
    for (; j + 3 < end; j += 4) {
        u32 pk = pairs[j + g];
        vu2 xv = xq[(size_t)(pk >> W_BITS) * 16 + m];
        float wf = (float)(pk & W_MASK) * W_INV;
        float2 lo = h2f(xv.x);
        float2 hi = h2f(xv.y);
        ax = fmaf(wf, lo.x, ax); ay = fmaf(wf, lo.y, ay);
        az = fmaf(wf, hi.x, az); aw = fmaf(wf, hi.y, aw);
    }
    // tail (<4): only group 0 accumulates
    for (; j < end; ++j) {
        u32 pk = pairs[j];
        vu2 xv = xq[(size_t)(pk >> W_BITS) * 16 + m];
        float wf = (g == 0) ? (float)(pk & W_MASK) * W_INV : 0.f;
        float2 lo = h2f(xv.x);
        float2 hi = h2f(xv.y);
        ax = fmaf(wf, lo.x, ax); ay = fmaf(wf, lo.y, ay);
        az = fmaf(wf, hi.x, az); aw = fmaf(wf, hi.y, aw);
    }

    // combine the 4 groups: xor over the two group bits (lanes 16, 32 apart)
    ax += __shfl_xor(ax, 16); ax += __shfl_xor(ax, 32);
    ay += __shfl_xor(ay, 16); ay += __shfl_xor(ay, 32);
    az += __shfl_xor(az, 16); az += __shfl_xor(az, 32);
    aw += __shfl_xor(aw, 16); aw += __shfl_xor(aw, 32);

    if (lane < 16) {
        ushort4 h;
        h.x = __half_as_ushort(__float2half_rn(ax));
        h.y = __half_as_ushort(__float2half_rn(ay));
        h.z = __half_as_ushort(__float2half_rn(az));
        h.w = __half_as_ushort(__float2half_rn(aw));
        ((ushort4*)nxt)[(size_t)wave * 16 + m] = h;
    }
}

// ---------------------------------------------------------------------------
// k_fin: out = (ego + e1 + e2 + e3) * 0.25   (streaming)
// ---------------------------------------------------------------------------
__global__ void k_fin(const float4* __restrict__ user,
                      const float4* __restrict__ item,
                      const ushort4* __restrict__ e1,
                      const ushort4* __restrict__ e2,
                      const ushort4* __restrict__ e3,
                      float4* __restrict__ out) {
    int i = blockIdx.x * blockDim.x + threadIdx.x;
    const int total4 = N_NODES * EMB / 4;
    const int user4  = N_USERS * EMB / 4;
    if (i >= total4) return;
    float4 v = (i < user4) ? user[i] : item[i - user4];
    ushort4 a = e1[i], b = e2[i], c = e3[i];
    v.x = (v.x + __half2float(__ushort_as_half(a.x))
              + __half2float(__ushort_as_half(b.x))
              + __half2float(__ushort_as_half(c.x))) * 0.25f;
    v.y = (v.y + __half2float(__ushort_as_half(a.y))
              + __half2float(__ushort_as_half(b.y))
              + __half2float(__ushort_as_half(c.y))) * 0.25f;
    v.z = (v.z + __half2float(__ushort_as_half(a.z))
              + __half2float(__ushort_as_half(b.z))
              + __half2float(__ushort_as_half(c.z))) * 0.25f;
    v.w = (v.w + __half2float(__ushort_as_half(a.w))
              + __half2float(__ushort_as_half(b.w))
              + __half2float(__ushort_as_half(c.w))) * 0.25f;
    __builtin_nontemporal_store(v.x, &((float*)out)[4 * (size_t)i + 0]);
    __builtin_nontemporal_store(v.y, &((float*)out)[4 * (size_t)i + 1]);
    __builtin_nontemporal_store(v.z, &((float*)out)[4 * (size_t)i + 2]);
    __builtin_nontemporal_store(v.w, &((float*)out)[4 * (size_t)i + 3]);
}

// ---------------------------------------------------------------------------
// Fallback (R1 atomic path, fp32) if workspace is too small
// ---------------------------------------------------------------------------
__global__ void k_spmm(const int*   __restrict__ src,
                       const int*   __restrict__ dst,
                       const float* __restrict__ w,
                       const float* __restrict__ x,
                       float*       __restrict__ y) {
    long long t = (long long)blockIdx.x * blockDim.x + threadIdx.x;
    int e = (int)(t >> 4);
    if (e >= N_EDGES) return;
    int q = (int)(t & 15);
    int   s  = src[e];
    int   d  = dst[e];
    float we = w[e];
    const float4* xs = (const float4*)(x + (long long)s * EMB);
    float4 v = xs[q];
    float* yd = y + (long long)d * EMB + q * 4;
    atomicAdd(yd + 0, we * v.x);
    atomicAdd(yd + 1, we * v.y);
    atomicAdd(yd + 2, we * v.z);
    atomicAdd(yd + 3, we * v.w);
}

__global__ void k_init_f32(const float4* __restrict__ user,
                           const float4* __restrict__ item,
                           float4* __restrict__ out,
                           float4* __restrict__ cur) {
    int i = blockIdx.x * blockDim.x + threadIdx.x;
    const int total4 = N_NODES * EMB / 4;
    const int user4  = N_USERS * EMB / 4;
    if (i >= total4) return;
    float4 v = (i < user4) ? user[i] : item[i - user4];
    out[i] = v;
    cur[i] = v;
}

__global__ void k_acc(float4* __restrict__ out,
                      const float4* __restrict__ buf,
                      float scale) {
    int i = blockIdx.x * blockDim.x + threadIdx.x;
    const int total4 = N_NODES * EMB / 4;
    if (i >= total4) return;
    float4 o = out[i];
    float4 b = buf[i];
    o.x = (o.x + b.x) * scale;
    o.y = (o.y + b.y) * scale;
    o.z = (o.z + b.z) * scale;
    o.w = (o.w + b.w) * scale;
    out[i] = o;
}

extern "C" void kernel_launch(void* const* d_in, const int* in_sizes, int n_in,
                              void* d_out, int out_size, void* d_ws, size_t ws_size,
                              hipStream_t stream) {
    const float* user_emb = (const float*)d_in[0];
    const float* item_emb = (const float*)d_in[1];
    const float* edge_w   = (const float*)d_in[2];
    const int*   edge_src = (const int*)d_in[3];
    const int*   edge_dst = (const int*)d_in[4];
    float* out = (float*)d_out;

    const size_t feat_elems = (size_t)N_NODES * EMB;            // 9.6M
    const size_t feat_bytes_f32 = feat_elems * 4;               // 38.4 MB
    const size_t feat_bytes_f16 = feat_elems * 2;               // 19.2 MB

    // ---- workspace layout (identical to R8 — known to fit) ----
    char* ws = (char*)d_ws;
    size_t off = 0;
    __half* h0 = (__half*)(ws + off); off += feat_bytes_f16;
    __half* h1 = (__half*)(ws + off); off += feat_bytes_f16;
    __half* h2 = (__half*)(ws + off); off += feat_bytes_f16;
    __half* h3 = (__half*)(ws + off); off += feat_bytes_f16;
    int* row_ptr  = (int*)(ws + off); off += ((size_t)(N_NODES + 1) * 4 + 63) / 64 * 64;
    int* cursor   = (int*)(ws + off); off += (size_t)NREP * NBKT * 4;
    int* bkt_base = (int*)(ws + off); off += (size_t)NBKT * 4;
    u32* pk_arr = (u32*)(ws + off);   off += (size_t)NBKT * CAP * 4;   // 21.5 MB
    u16* ld_arr = (u16*)(ws + off);   off += (size_t)NBKT * CAP * 2;   // 10.7 MB
    u32* pairs  = (u32*)(ws + off);   off += (size_t)N_EDGES * 4;      // 19.2 MB
    const size_t needed = off;

    const int block = 256;
    const int total4 = (int)(feat_elems / 4);
    const int fgrid = (total4 + block - 1) / block;
    const int p1grid = (N_EDGES / 8 + block - 1) / block;   // 2344
    const int ggrid = (N_NODES + 3) / 4;                    // 4 waves / 256-thread block

    if (ws_size >= needed) {
        (void)hipMemsetAsync(cursor, 0, (size_t)NREP * NBKT * 4, stream);

        k_init<<<fgrid, block, 0, stream>>>((const float4*)user_emb,
                                            (const float4*)item_emb,
                                            (ushort4*)h0);

        k_p1<<<p1grid, block, 0, stream>>>((const int4*)edge_src,
                                           (const int4*)edge_dst,
                                           (const float4*)edge_w,
                                           cursor, pk_arr, ld_arr);
        k_scan256<<<1, NBKT, 0, stream>>>(cursor, bkt_base, row_ptr);
        k_p2<<<NBKT, 1024, 0, stream>>>(cursor, bkt_base, pk_arr, ld_arr,
                                        row_ptr, pairs);

        __half* bufs[4] = {h0, h1, h2, h3};
        for (int layer = 0; layer < N_LAYERS; ++layer)
            k_gather<<<ggrid, block, 0, stream>>>(row_ptr, pairs,
                                                  bufs[layer], bufs[layer + 1]);

        k_fin<<<fgrid, block, 0, stream>>>((const float4*)user_emb,
                                           (const float4*)item_emb,
                                           (const ushort4*)h1,
                                           (const ushort4*)h2,
                                           (const ushort4*)h3,
                                           (float4*)out);
    } else {
        // atomic fallback (fp32) — needs 2 x 38.4 MB
        float* buf0 = (float*)d_ws;
        float* buf1 = buf0 + feat_elems;
        k_init_f32<<<fgrid, block, 0, stream>>>((const float4*)user_emb,
                                                (const float4*)item_emb,
                                                (float4*)out, (float4*)buf0);
        float* cur = buf0;
        float* nxt = buf1;
        for (int layer = 0; layer < N_LAYERS; ++layer) {
            (void)hipMemsetAsync(nxt, 0, feat_bytes_f32, stream);
            long long threads = (long long)N_EDGES * 16;
            int grid = (int)((threads + block - 1) / block);
            k_spmm<<<grid, block, 0, stream>>>(edge_src, edge_dst, edge_w, cur, nxt);
            float scale = (layer == N_LAYERS - 1) ? (1.0f / (N_LAYERS + 1)) : 1.0f;
            k_acc<<<fgrid, block, 0, stream>>>((float4*)out, (const float4*)nxt, scale);
            float* tmp = cur; cur = nxt; nxt = tmp;
        }
    }
}